// Round 8
// baseline (787.841 us; speedup 1.0000x reference)
//
#include <hip/hip_runtime.h>
#include <hip/hip_bf16.h>
#include <math.h>

#define CD 128
#define HH 4
#define DH 32
#define LL 2

using bf16 = __hip_bfloat16;
using bf16x8 = __attribute__((ext_vector_type(8))) short;  // 8 bf16 (4 VGPRs)
using f32x4 = __attribute__((ext_vector_type(4))) float;

__device__ __forceinline__ float bfbits2f(unsigned int s) {
  return __uint_as_float(s << 16);
}

__device__ __forceinline__ unsigned short f2bfbits(float f) {
  unsigned int u = __float_as_uint(f);
  unsigned int r = (u + 0x7fff + ((u >> 16) & 1)) >> 16;  // RNE
  return (unsigned short)r;
}

__device__ __forceinline__ float gelu_f(float x) {
  return 0.5f * x * (1.0f + erff(x * 0.70710678118654752f));
}

// ---- detect input formats: flags[0]=floats-are-f32, flags[1]=edge-index-is-i64 ----
__global__ void k_detect(const void* __restrict__ x, const int* __restrict__ ei,
                         int* __restrict__ flags) {
  __shared__ int cnt_f32, cnt_i32;
  if (threadIdx.x == 0) { cnt_f32 = 0; cnt_i32 = 0; }
  __syncthreads();
  int t = threadIdx.x;  // 128 threads
  unsigned short u = ((const unsigned short*)x)[2 * t];
  float v = bfbits2f((unsigned int)u);
  float av = fabsf(v);
  if (av != 0.f && (av > 1e8f || av < 1e-8f)) atomicAdd(&cnt_f32, 1);
  if (t < 64) {
    if (((const int*)ei)[2 * t + 1] != 0) atomicAdd(&cnt_i32, 1);
  }
  __syncthreads();
  if (threadIdx.x == 0) {
    flags[0] = (cnt_f32 > 8) ? 1 : 0;
    flags[1] = (cnt_i32 == 0) ? 1 : 0;
  }
}

#define NSEG 14
struct SegTab {
  const void* src[NSEG];
  int off[NSEG];
  int total;
};

__device__ __forceinline__ int edge_idx(const int* __restrict__ ei, long pos, int is64) {
  return is64 ? ei[2 * pos] : ei[pos];
}

#define BTILE 4096

// ==== FUSED pre-pass: {cvt_params, histb} (r5) ====
__global__ __launch_bounds__(256) void k_pre(
    SegTab tab, float* __restrict__ pdst,
    const int* __restrict__ ei, int* __restrict__ deg, int* __restrict__ bcnt,
    int E, int Nn, int shift, const int* __restrict__ flags, int parB) {
  __shared__ int cnt[256];
  const int bx = blockIdx.x;
  if (bx < parB) {
    int i = bx * 256 + threadIdx.x;
    if (i >= tab.total) return;
    int seg = 0;
#pragma unroll
    for (int k = 1; k < NSEG; k++)
      if (i >= tab.off[k]) seg = k;
    int j = i - tab.off[seg];
    const void* src = tab.src[seg];
    pdst[i] = flags[0] ? ((const float*)src)[j]
                       : bfbits2f((unsigned int)((const unsigned short*)src)[j]);
  } else {
    cnt[threadIdx.x] = 0;
    __syncthreads();
    const int t0 = (bx - parB) * BTILE;
    const int is64 = flags[1];
    for (int j = 0; j < 16; j++) {
      int i = t0 + threadIdx.x + j * 256;
      if (i < E) {
        int d = edge_idx(ei, (long)E + i, is64);
        if ((unsigned)d >= (unsigned)Nn) d = 0;
        atomicAdd(&deg[d], 1);
        atomicAdd(&cnt[d >> shift], 1);
      }
    }
    __syncthreads();
    int v = cnt[threadIdx.x];
    if (v > 0) atomicAdd(&bcnt[threadIdx.x], v);
  }
}

// ==== FUSED stage 2: {eff, wt, scan1} (r4, unchanged) ====
__global__ __launch_bounds__(256) void k_w1(
    const float* __restrict__ pWk, const float* __restrict__ pbk,
    const float* __restrict__ pWv, const float* __restrict__ pbv,
    const float* __restrict__ par, const float* __restrict__ pmr,
    unsigned short* __restrict__ wkeT, float* __restrict__ bke,
    unsigned short* __restrict__ wveT, float* __restrict__ bve,
    const float* __restrict__ pWq, const float* __restrict__ pWa,
    unsigned short* __restrict__ wqT, unsigned short* __restrict__ waT,
    const int* __restrict__ deg, int* __restrict__ tmp, int* __restrict__ bsum,
    int n, int effB, int wtB) {
  __shared__ int sh[256];
  const int bx = blockIdx.x;
  if (bx < effB) {
    int i = bx * 256 + threadIdx.x;
    const int total = LL * 2 * (CD + 1) * HH * DH;
    if (i >= total) return;
    int e = i & 31;
    int h = (i >> 5) & 3;
    int c = (i >> 7) % (CD + 1);
    int z = (i >> 7) / (CD + 1);
    int l = z >> 1, which = z & 1;
    const float* W = (which ? pWv : pWk) + (size_t)l * CD * CD;
    const float* B = (which ? pbv : pbk) + (size_t)l * CD;
    const float* R = (which ? pmr : par) + (size_t)l * HH * DH * DH + h * DH * DH;
    unsigned short* WoT = (which ? wveT : wkeT) + (size_t)l * CD * CD;
    float* Bo = (which ? bve : bke) + (size_t)l * CD;
    float acc = 0.f;
    if (c < CD) {
#pragma unroll
      for (int d = 0; d < DH; d++) acc += W[c * CD + h * DH + d] * R[d * DH + e];
      WoT[(size_t)(h * DH + e) * CD + c] = f2bfbits(acc);
    } else {
#pragma unroll
      for (int d = 0; d < DH; d++) acc += B[h * DH + d] * R[d * DH + e];
      Bo[h * DH + e] = acc;
    }
  } else if (bx < effB + wtB) {
    int i = (bx - effB) * 256 + threadIdx.x;  // < LL*2*CD*CD exactly
    int cin = i & 127;
    int cout = (i >> 7) & 127;
    int z = i >> 14;
    int l = z >> 1, which = z & 1;
    const float* W = (which ? pWa : pWq) + (size_t)l * CD * CD;
    unsigned short* WT = (which ? waT : wqT) + (size_t)l * CD * CD;
    WT[(size_t)cout * CD + cin] = f2bfbits(W[(size_t)cin * CD + cout]);
  } else {
    const int b = bx - effB - wtB;
    int i = b * 256 + threadIdx.x;
    int v = (i < n) ? deg[i] : 0;
    sh[threadIdx.x] = v;
    __syncthreads();
    for (int off = 1; off < 256; off <<= 1) {
      int t = (threadIdx.x >= off) ? sh[threadIdx.x - off] : 0;
      __syncthreads();
      sh[threadIdx.x] += t;
      __syncthreads();
    }
    if (i < n) tmp[i] = sh[threadIdx.x];
    if (threadIdx.x == 255) bsum[b] = sh[255];
  }
}

// ==== FUSED stage 3: {scan2, bscan} (r4, unchanged) ====
__global__ __launch_bounds__(256) void k_s2(
    int* __restrict__ bsum, int nb, const int* __restrict__ bcnt,
    int* __restrict__ bbase, int* __restrict__ bfill) {
  __shared__ int sh[256];
  __shared__ int carry;
  if (blockIdx.x == 0) {
    if (threadIdx.x == 0) carry = 0;
    __syncthreads();
    for (int base = 0; base < nb; base += 256) {
      int i = base + threadIdx.x;
      int v = (i < nb) ? bsum[i] : 0;
      sh[threadIdx.x] = v;
      __syncthreads();
      for (int off = 1; off < 256; off <<= 1) {
        int t = (threadIdx.x >= off) ? sh[threadIdx.x - off] : 0;
        __syncthreads();
        sh[threadIdx.x] += t;
        __syncthreads();
      }
      if (i < nb) bsum[i] = sh[threadIdx.x] + carry;
      __syncthreads();
      if (threadIdx.x == 0) carry += sh[255];
      __syncthreads();
    }
  } else {
    int t = threadIdx.x;
    int v = bcnt[t];
    sh[t] = v;
    __syncthreads();
    for (int off = 1; off < 256; off <<= 1) {
      int u = (t >= off) ? sh[t - off] : 0;
      __syncthreads();
      sh[t] += u;
      __syncthreads();
    }
    int excl = sh[t] - v;
    bbase[t] = excl;
    bfill[t] = excl;
  }
}

// ==== FUSED stage 4: {scan3, bin} (r4, unchanged) ====
__global__ __launch_bounds__(256) void k_s3bin(
    const int* __restrict__ tmp, const int* __restrict__ deg,
    const int* __restrict__ bsum, int* __restrict__ rowptr,
    int* __restrict__ fill, int n, int nB,
    const int* __restrict__ ei, int* __restrict__ bfill,
    int* __restrict__ ebs, int* __restrict__ ebd,
    const int* __restrict__ flags, int E, int Nn, int shift) {
  __shared__ int sS[BTILE];
  __shared__ int sD[BTILE];
  __shared__ int cnt[256], pref[256], base[256], lofs[256];
  const int bx = blockIdx.x;
  if (bx < nB) {
    int i = bx * 256 + threadIdx.x;
    if (i >= n) return;
    int off = (bx > 0) ? bsum[bx - 1] : 0;
    int excl = tmp[i] - deg[i] + off;
    rowptr[i] = excl;
    fill[i] = excl;
    return;
  }
  const int t = threadIdx.x;
  cnt[t] = 0;
  lofs[t] = 0;
  __syncthreads();
  const int t0 = (bx - nB) * BTILE;
  const int is64 = flags[1];
  for (int j = 0; j < 16; j++) {
    int i = t0 + t + j * 256;
    if (i < E) {
      int d = edge_idx(ei, (long)E + i, is64);
      if ((unsigned)d >= (unsigned)Nn) d = 0;
      atomicAdd(&cnt[d >> shift], 1);
    }
  }
  __syncthreads();
  {
    int v = cnt[t];
    pref[t] = v;
    __syncthreads();
    for (int off = 1; off < 256; off <<= 1) {
      int u = (t >= off) ? pref[t - off] : 0;
      __syncthreads();
      pref[t] += u;
      __syncthreads();
    }
    int incl = pref[t];
    __syncthreads();
    pref[t] = incl - v;
    base[t] = (v > 0) ? atomicAdd(&bfill[t], v) : 0;
  }
  __syncthreads();
  for (int j = 0; j < 16; j++) {
    int i = t0 + t + j * 256;
    if (i < E) {
      int s = edge_idx(ei, (long)i, is64);
      int d = edge_idx(ei, (long)E + i, is64);
      if ((unsigned)s >= (unsigned)Nn) s = 0;
      if ((unsigned)d >= (unsigned)Nn) d = 0;
      int b = d >> shift;
      int p = pref[b] + atomicAdd(&lofs[b], 1);
      sS[p] = s;
      sD[p] = d;
    }
  }
  __syncthreads();
  int tot = E - t0;
  if (tot > BTILE) tot = BTILE;
  for (int j = 0; j < 16; j++) {
    int i = t + j * 256;
    if (i < tot) {
      int d = sD[i];
      int b = d >> shift;
      int gp = base[b] + (i - pref[b]);
      ebs[gp] = sS[i];
      ebd[gp] = d;
    }
  }
}

// final scatter within per-bucket csr window (L2-local)
__global__ void k_scatter2(const int* __restrict__ bbase, const int* __restrict__ bcnt,
                           const int* __restrict__ ebs, const int* __restrict__ ebd,
                           int* __restrict__ fill, int* __restrict__ csr_src) {
  int b = blockIdx.x >> 1, half = blockIdx.x & 1;
  int s0 = bbase[b], c = bcnt[b];
  int st = s0 + (half ? (c + 1) / 2 : 0);
  int en = s0 + (half ? c : (c + 1) / 2);
  for (int i = st + threadIdx.x; i < en; i += 256) {
    int s = ebs[i], d = ebd[i];
    int pos = atomicAdd(&fill[d], 1);
    csr_src[pos] = s;
  }
}

// ==== fused q/k/v MFMA GEMM for layer 0, reading raw x (r5, unchanged).
// grid.y selects projection. ====
__global__ __launch_bounds__(256) void k_gemm_qkv(
    const void* __restrict__ Araw, int a_is_x, const int* __restrict__ flags,
    const unsigned short* __restrict__ wq, const unsigned short* __restrict__ wk,
    const unsigned short* __restrict__ wv,
    const float* __restrict__ bq, const float* __restrict__ bk,
    const float* __restrict__ bv,
    float* __restrict__ qout, unsigned short* __restrict__ kvout, int nrows) {
  const int which = blockIdx.y;
  const unsigned short* BT = (which == 0) ? wq : (which == 1) ? wk : wv;
  const float* bias = (which == 0) ? bq : (which == 1) ? bk : bv;
  const int w = threadIdx.x >> 6;
  const int l = threadIdx.x & 63;
  const int r0 = blockIdx.x * 64 + w * 16;
  if (r0 >= nrows) return;
  const int lrow = l & 15;
  const int quad = l >> 4;
  const int k0 = quad * 8;
  const int ax_f32 = a_is_x ? flags[0] : 0;

  f32x4 acc[8];
#pragma unroll
  for (int ct = 0; ct < 8; ct++) {
    float b = bias[ct * 16 + lrow];
    acc[ct] = (f32x4){b, b, b, b};
  }
  int ar = r0 + lrow;
  if (ar >= nrows) ar = nrows - 1;
#pragma unroll
  for (int kc = 0; kc < 4; kc++) {
    bf16x8 af;
    if (ax_f32) {
      const float* Af = (const float*)Araw + (size_t)ar * CD + kc * 32 + k0;
      float4 a = *(const float4*)Af;
      float4 b = *(const float4*)(Af + 4);
      af[0] = (short)f2bfbits(a.x); af[1] = (short)f2bfbits(a.y);
      af[2] = (short)f2bfbits(a.z); af[3] = (short)f2bfbits(a.w);
      af[4] = (short)f2bfbits(b.x); af[5] = (short)f2bfbits(b.y);
      af[6] = (short)f2bfbits(b.z); af[7] = (short)f2bfbits(b.w);
    } else {
      af = *(const bf16x8*)((const unsigned short*)Araw + (size_t)ar * CD + kc * 32 + k0);
    }
#pragma unroll
    for (int ct = 0; ct < 8; ct++) {
      bf16x8 bfr = *(const bf16x8*)(BT + (size_t)(ct * 16 + lrow) * CD + kc * 32 + k0);
      acc[ct] = __builtin_amdgcn_mfma_f32_16x16x32_bf16(af, bfr, acc[ct], 0, 0, 0);
    }
  }
#pragma unroll
  for (int ct = 0; ct < 8; ct++) {
#pragma unroll
    for (int i = 0; i < 4; i++) {
      int gr = r0 + quad * 4 + i;
      if (gr >= nrows) continue;
      int col = ct * 16 + lrow;
      float val = acc[ct][i];
      if (which == 0) {
        qout[(size_t)gr * CD + col] = val;
      } else {
        unsigned short* o = kvout + ((size_t)gr << 8) + ((which == 2) ? CD : 0);
        o[col] = f2bfbits(val);
      }
    }
  }
}

// ==== FUSED gate-l0 + qkv-l1 (r8 fix): r7's `#pragma unroll` on the which-
// loop fully unrolled the 3 projections -> scheduler interleaved them ->
// 96+ acc AGPRs live (r3's pathology reborn) -> 28.8% occupancy, 166 us,
// all pipes idle. Fix: `#pragma unroll 1` FORCES sequential projections
// (one 32-reg accumulator at a time); A-frags hoisted from LDS to 16 VGPRs
// once. Math bit-identical. ====
__global__ __launch_bounds__(256) void k_gate_qkv(
    const unsigned short* __restrict__ A, const unsigned short* __restrict__ BTa,
    const float* __restrict__ ba, const void* __restrict__ xres,
    float* __restrict__ h, const float* __restrict__ skip,
    const int* __restrict__ flags,
    const unsigned short* __restrict__ wq1, const unsigned short* __restrict__ wk1,
    const unsigned short* __restrict__ wv1,
    const float* __restrict__ bq1, const float* __restrict__ bk1,
    const float* __restrict__ bv1,
    float* __restrict__ qout, unsigned short* __restrict__ kvout, int nrows) {
  __shared__ unsigned short sA[64][136];
  const int w = threadIdx.x >> 6;
  const int l = threadIdx.x & 63;
  const int blkbase = blockIdx.x * 64;
  const int r0 = blkbase + w * 16;
  const int lrow = l & 15;
  const int quad = l >> 4;
  const int k0 = quad * 8;
  const int xf32 = flags[0];

  // ---- phase 1: gate for this wave's 16 rows ----
  if (r0 < nrows) {
    f32x4 acc[8];
#pragma unroll
    for (int ct = 0; ct < 8; ct++) {
      float b = ba[ct * 16 + lrow];
      acc[ct] = (f32x4){b, b, b, b};
    }
    int ar = r0 + lrow;
    if (ar >= nrows) ar = nrows - 1;
    const unsigned short* Ap = A + (size_t)ar * CD;
#pragma unroll
    for (int kc = 0; kc < 4; kc++) {
      bf16x8 af = *(const bf16x8*)(Ap + kc * 32 + k0);
#pragma unroll
      for (int ct = 0; ct < 8; ct++) {
        bf16x8 bfr = *(const bf16x8*)(BTa + (size_t)(ct * 16 + lrow) * CD + kc * 32 + k0);
        acc[ct] = __builtin_amdgcn_mfma_f32_16x16x32_bf16(af, bfr, acc[ct], 0, 0, 0);
      }
    }
    float gg = 1.f / (1.f + __expf(-skip[0]));
#pragma unroll
    for (int ct = 0; ct < 8; ct++) {
#pragma unroll
      for (int i = 0; i < 4; i++) {
        int gr = r0 + quad * 4 + i;
        if (gr >= nrows) continue;
        size_t ix = (size_t)gr * CD + ct * 16 + lrow;
        float hres = xf32 ? ((const float*)xres)[ix]
                          : bfbits2f((unsigned int)((const unsigned short*)xres)[ix]);
        float o = gg * acc[ct][i] + (1.f - gg) * hres;
        h[ix] = o;
        sA[gr - blkbase][ct * 16 + lrow] = f2bfbits(o);
      }
    }
  }
  __syncthreads();
  if (r0 >= nrows) return;

  // ---- phase 2: qkv-l1; A-frags hoisted to regs, projections SEQUENTIAL ----
  int ar = r0 + lrow;
  if (ar >= nrows) ar = nrows - 1;
  bf16x8 afr[4];
#pragma unroll
  for (int kc = 0; kc < 4; kc++)
    afr[kc] = *(const bf16x8*)(&sA[ar - blkbase][kc * 32 + k0]);
#pragma unroll 1
  for (int which = 0; which < 3; which++) {
    const unsigned short* BT = (which == 0) ? wq1 : (which == 1) ? wk1 : wv1;
    const float* bias = (which == 0) ? bq1 : (which == 1) ? bk1 : bv1;
    f32x4 acc[8];
#pragma unroll
    for (int ct = 0; ct < 8; ct++) {
      float b = bias[ct * 16 + lrow];
      acc[ct] = (f32x4){b, b, b, b};
    }
#pragma unroll
    for (int kc = 0; kc < 4; kc++) {
#pragma unroll
      for (int ct = 0; ct < 8; ct++) {
        bf16x8 bfr = *(const bf16x8*)(BT + (size_t)(ct * 16 + lrow) * CD + kc * 32 + k0);
        acc[ct] = __builtin_amdgcn_mfma_f32_16x16x32_bf16(afr[kc], bfr, acc[ct], 0, 0, 0);
      }
    }
#pragma unroll
    for (int ct = 0; ct < 8; ct++) {
#pragma unroll
      for (int i = 0; i < 4; i++) {
        int gr = r0 + quad * 4 + i;
        if (gr >= nrows) continue;
        int col = ct * 16 + lrow;
        float val = acc[ct][i];
        if (which == 0) {
          qout[(size_t)gr * CD + col] = val;
        } else {
          unsigned short* o = kvout + ((size_t)gr << 8) + ((which == 2) ? CD : 0);
          o[col] = f2bfbits(val);
        }
      }
    }
  }
}

// ==== gate MFMA GEMM, FINAL layer only (r6): gelu(agg)@Wa + ba, gated
// residual from h f32, fused 128x2 output projection (r5, passed). ====
__global__ __launch_bounds__(256) void k_gemm_gate(
    const unsigned short* __restrict__ A, const unsigned short* __restrict__ BT,
    const float* __restrict__ bias, const float* __restrict__ h,
    const float* __restrict__ skip,
    const float* __restrict__ Wfc, const float* __restrict__ bfc,
    void* __restrict__ out, const int* __restrict__ flags, int nrows) {
  const int w = threadIdx.x >> 6;
  const int l = threadIdx.x & 63;
  const int r0 = blockIdx.x * 64 + w * 16;
  if (r0 >= nrows) return;
  const int lrow = l & 15;
  const int quad = l >> 4;
  const int k0 = quad * 8;
  const int xf32 = flags[0];

  f32x4 acc[8];
#pragma unroll
  for (int ct = 0; ct < 8; ct++) {
    float b = bias[ct * 16 + lrow];
    acc[ct] = (f32x4){b, b, b, b};
  }
  int ar = r0 + lrow;
  if (ar >= nrows) ar = nrows - 1;
  const unsigned short* Ap = A + (size_t)ar * CD;
#pragma unroll
  for (int kc = 0; kc < 4; kc++) {
    bf16x8 af = *(const bf16x8*)(Ap + kc * 32 + k0);
#pragma unroll
    for (int ct = 0; ct < 8; ct++) {
      bf16x8 bfr = *(const bf16x8*)(BT + (size_t)(ct * 16 + lrow) * CD + kc * 32 + k0);
      acc[ct] = __builtin_amdgcn_mfma_f32_16x16x32_bf16(af, bfr, acc[ct], 0, 0, 0);
    }
  }
  float gg = 1.f / (1.f + __expf(-skip[0]));
  float p0[4] = {0.f, 0.f, 0.f, 0.f};
  float p1[4] = {0.f, 0.f, 0.f, 0.f};
#pragma unroll
  for (int ct = 0; ct < 8; ct++) {
    float w0 = Wfc[(ct * 16 + lrow) * 2];
    float w1 = Wfc[(ct * 16 + lrow) * 2 + 1];
#pragma unroll
    for (int i = 0; i < 4; i++) {
      int gr = r0 + quad * 4 + i;
      if (gr >= nrows) continue;
      size_t ix = (size_t)gr * CD + ct * 16 + lrow;
      float o = gg * acc[ct][i] + (1.f - gg) * h[ix];
      p0[i] += o * w0;
      p1[i] += o * w1;
    }
  }
#pragma unroll
  for (int off = 1; off <= 8; off <<= 1) {
#pragma unroll
    for (int i = 0; i < 4; i++) {
      p0[i] += __shfl_xor(p0[i], off);
      p1[i] += __shfl_xor(p1[i], off);
    }
  }
  if (lrow == 0) {
#pragma unroll
    for (int i = 0; i < 4; i++) {
      int gr = r0 + quad * 4 + i;
      if (gr >= nrows) continue;
      float o0 = p0[i] + bfc[0];
      float o1 = p1[i] + bfc[1];
      if (xf32) {
        ((float*)out)[(size_t)gr * 2] = o0;
        ((float*)out)[(size_t)gr * 2 + 1] = o1;
      } else {
        ((bf16*)out)[(size_t)gr * 2] = __float2bfloat16(o0);
        ((bf16*)out)[(size_t)gr * 2 + 1] = __float2bfloat16(o1);
      }
    }
  }
}

// ---- per-edge compute: unpack k/v, dot with q, exp, accumulate ----
__device__ __forceinline__ void edge_acc(uint4 ku, uint4 vu, float4 qa, float4 qb,
                                         float* __restrict__ acc, float& den) {
  float k0 = bfbits2f(ku.x & 0xffffu), k1 = bfbits2f(ku.x >> 16);
  float k2 = bfbits2f(ku.y & 0xffffu), k3 = bfbits2f(ku.y >> 16);
  float k4 = bfbits2f(ku.z & 0xffffu), k5 = bfbits2f(ku.z >> 16);
  float k6 = bfbits2f(ku.w & 0xffffu), k7 = bfbits2f(ku.w >> 16);
  float v0 = bfbits2f(vu.x & 0xffffu), v1 = bfbits2f(vu.x >> 16);
  float v2 = bfbits2f(vu.y & 0xffffu), v3 = bfbits2f(vu.y >> 16);
  float v4 = bfbits2f(vu.z & 0xffffu), v5 = bfbits2f(vu.z >> 16);
  float v6 = bfbits2f(vu.w & 0xffffu), v7 = bfbits2f(vu.w >> 16);
  float pd = qa.x * k0 + qa.y * k1 + qa.z * k2 + qa.w * k3 +
             qb.x * k4 + qb.y * k5 + qb.z * k6 + qb.w * k7;
  pd += __shfl_xor(pd, 1);
  pd += __shfl_xor(pd, 2);
  float ew = __expf(fminf(pd, 60.f));  // no max-sub: |logit| ~ O(1), safe
  acc[0] += ew * v0; acc[1] += ew * v1;
  acc[2] += ew * v2; acc[3] += ew * v3;
  acc[4] += ew * v4; acc[5] += ew * v5;
  acc[6] += ew * v6; acc[7] += ew * v7;
  den += ew;
}

// ==== fused attention (unchanged; pinned at the random-256B-gather
// throughput ceiling ~3.75 TB/s across 3 schedules / occupancies 67-77%). ====
__global__ __launch_bounds__(256) void k_edge(
    const float* __restrict__ q, const unsigned short* __restrict__ kv,
    const int* __restrict__ rowptr, const int* __restrict__ deg,
    const int* __restrict__ csr_src, const float* __restrict__ p_rel,
    unsigned short* __restrict__ agg16, int N) {
  int n = (blockIdx.x * 256 + threadIdx.x) >> 6;
  if (n >= N) return;
  const int lane = threadIdx.x & 63;
  const int g = lane >> 4;
  const int j = lane & 15;
  const int start = rowptr[n];
  const int end = start + deg[n];
  const float prl = p_rel[j >> 2] * 0.17677669529663687f;  // 1/sqrt(32)
  float4 qa = *(const float4*)(q + (size_t)n * CD + 8 * j);
  float4 qb = *(const float4*)(q + (size_t)n * CD + 8 * j + 4);
  qa.x *= prl; qa.y *= prl; qa.z *= prl; qa.w *= prl;
  qb.x *= prl; qb.y *= prl; qb.z *= prl; qb.w *= prl;
  float den = 0.f;
  float acc[8] = {0.f, 0.f, 0.f, 0.f, 0.f, 0.f, 0.f, 0.f};
  int e = start + g;
  if (e < end) {
    const int last = end - 1;
    bool bok = (e + 4) < end;
    int sa = csr_src[e];
    int sb = csr_src[bok ? e + 4 : e];
    const unsigned short* pa = kv + ((size_t)sa << 8) + 8 * j;
    const unsigned short* pb = kv + ((size_t)sb << 8) + 8 * j;
    uint4 kua = *(const uint4*)pa;
    uint4 vua = *(const uint4*)(pa + CD);
    uint4 kub = *(const uint4*)pb;
    uint4 vub = *(const uint4*)(pb + CD);
    for (;;) {
      const int en = e + 8;
      int ea2 = (en < last) ? en : last;
      int eb2 = (en + 4 < last) ? en + 4 : last;
      int sa2 = csr_src[ea2];
      int sb2 = csr_src[eb2];
      const unsigned short* pa2 = kv + ((size_t)sa2 << 8) + 8 * j;
      const unsigned short* pb2 = kv + ((size_t)sb2 << 8) + 8 * j;
      uint4 kua2 = *(const uint4*)pa2;
      uint4 vua2 = *(const uint4*)(pa2 + CD);
      uint4 kub2 = *(const uint4*)pb2;
      uint4 vub2 = *(const uint4*)(pb2 + CD);
      __builtin_amdgcn_sched_barrier(0);
      edge_acc(kua, vua, qa, qb, acc, den);
      if (bok) edge_acc(kub, vub, qa, qb, acc, den);
      if (en >= end) break;
      e = en;
      bok = (en + 4) < end;
      kua = kua2; vua = vua2; kub = kub2; vub = vub2;
    }
  }
#pragma unroll
  for (int off = 16; off <= 32; off <<= 1) {
    den += __shfl_xor(den, off);
#pragma unroll
    for (int i = 0; i < 8; i++) acc[i] += __shfl_xor(acc[i], off);
  }
  if (g == 0) {
    float inv = (den > 0.f) ? 1.f / den : 0.f;
    ushort4 o0, o1;
    o0.x = f2bfbits(gelu_f(acc[0] * inv)); o0.y = f2bfbits(gelu_f(acc[1] * inv));
    o0.z = f2bfbits(gelu_f(acc[2] * inv)); o0.w = f2bfbits(gelu_f(acc[3] * inv));
    o1.x = f2bfbits(gelu_f(acc[4] * inv)); o1.y = f2bfbits(gelu_f(acc[5] * inv));
    o1.z = f2bfbits(gelu_f(acc[6] * inv)); o1.w = f2bfbits(gelu_f(acc[7] * inv));
    *(ushort4*)(agg16 + (size_t)n * CD + 8 * j) = o0;
    *(ushort4*)(agg16 + (size_t)n * CD + 8 * j + 4) = o1;
  }
}

extern "C" void kernel_launch(void* const* d_in, const int* in_sizes, int n_in,
                              void* d_out, int out_size, void* d_ws, size_t ws_size,
                              hipStream_t stream) {
  const int* ei = (const int*)d_in[1];
  const int N = in_sizes[0] / CD;
  const int E = in_sizes[1] / 2;
  const size_t NC = (size_t)N * CD;
  const int nB = (N + 255) / 256;
  int shift = 0;
  while (((N - 1) >> shift) >= 256) shift++;  // 256 coarse buckets

  float* p = (float*)d_ws;
  float* hbuf = p;                                    // NC f32 (h1 storage)
  float* qbuf = p + NC;                               // NC f32
  float* cur = p + 2 * NC;
  unsigned short* kvbuf16 = (unsigned short*)cur; cur += NC;  // N x 256 bf16 (k|v)
  unsigned short* agg16 = (unsigned short*)cur; cur += NC / 2;
  int* ip = (int*)cur;
  int* deg = ip;
  int* tmp = ip + N;
  int* rowptr = ip + 2 * N;
  int* fill = ip + 3 * N;
  int* bsum = ip + 4 * N;
  int* csr_src = ip + 4 * N + nB;
  int* bcnt = csr_src + E;     // 256
  int* bbase = bcnt + 256;     // 256
  int* bfill = bbase + 256;    // 256
  cur = (float*)(bfill + 256);
  unsigned short* wkeT = (unsigned short*)cur; cur += (size_t)LL * CD * CD / 2;
  unsigned short* wveT = (unsigned short*)cur; cur += (size_t)LL * CD * CD / 2;
  unsigned short* wqT = (unsigned short*)cur; cur += (size_t)LL * CD * CD / 2;
  unsigned short* waT = (unsigned short*)cur; cur += (size_t)LL * CD * CD / 2;
  float* bke = cur; cur += (size_t)LL * CD;
  float* bve = cur; cur += (size_t)LL * CD;
  float* pblock = cur;
  float* pWk = cur; cur += (size_t)LL * CD * CD;
  float* pbk = cur; cur += (size_t)LL * CD;
  float* pWq = cur; cur += (size_t)LL * CD * CD;
  float* pbq = cur; cur += (size_t)LL * CD;
  float* pWv = cur; cur += (size_t)LL * CD * CD;
  float* pbv = cur; cur += (size_t)LL * CD;
  float* par = cur; cur += (size_t)LL * HH * DH * DH;
  float* pmr = cur; cur += (size_t)LL * HH * DH * DH;
  float* ppr = cur; cur += (size_t)LL * HH;
  float* pWa = cur; cur += (size_t)LL * CD * CD;
  float* pba = cur; cur += (size_t)LL * CD;
  float* pskip = cur; cur += LL;
  float* pWfc = cur; cur += (size_t)CD * 2;
  float* pbfc = cur; cur += 2;
  int* flags = (int*)cur;

  // binned-edge staging aliases kvbuf16 (only used before layer loop)
  int* ebs = (int*)kvbuf16;      // E ints
  int* ebd = ebs + E;            // E ints

  SegTab tab;
  const int sizes[NSEG] = {LL * CD * CD, LL * CD, LL * CD * CD, LL * CD,
                           LL * CD * CD, LL * CD, LL * HH * DH * DH,
                           LL * HH * DH * DH, LL * HH, LL * CD * CD, LL * CD,
                           LL, CD * 2, 2};
  const int srcIdx[NSEG] = {2, 3, 4, 5, 6, 7, 8, 9, 10, 11, 12, 13, 14, 15};
  int off = 0;
  for (int k = 0; k < NSEG; k++) {
    tab.src[k] = d_in[srcIdx[k]];
    tab.off[k] = off;
    off += sizes[k];
  }
  tab.total = off;

  hipMemsetAsync(deg, 0, (size_t)N * sizeof(int), stream);
  hipMemsetAsync(bcnt, 0, 256 * sizeof(int), stream);
  k_detect<<<1, 128, 0, stream>>>(d_in[0], ei, flags);

  const int parB = (tab.total + 255) / 256;
  const int histB = (E + BTILE - 1) / BTILE;
  k_pre<<<parB + histB, 256, 0, stream>>>(tab, pblock, ei, deg, bcnt, E, N,
                                          shift, flags, parB);

  const int effB = (LL * 2 * (CD + 1) * HH * DH + 255) / 256;
  const int wtB = (LL * 2 * CD * CD) / 256;
  k_w1<<<effB + wtB + nB, 256, 0, stream>>>(
      pWk, pbk, pWv, pbv, par, pmr, wkeT, bke, wveT, bve,
      pWq, pWa, wqT, waT, deg, tmp, bsum, N, effB, wtB);

  k_s2<<<2, 256, 0, stream>>>(bsum, nB, bcnt, bbase, bfill);
  k_s3bin<<<nB + histB, 256, 0, stream>>>(tmp, deg, bsum, rowptr, fill, N, nB,
                                          ei, bfill, ebs, ebd, flags, E, N, shift);
  k_scatter2<<<512, 256, 0, stream>>>(bbase, bcnt, ebs, ebd, fill, csr_src);

  const int mfmaBlocks = (N + 63) / 64;

  // layer 0 qkv (from raw x)
  k_gemm_qkv<<<dim3(mfmaBlocks, 3), 256, 0, stream>>>(
      d_in[0], 1, flags, wqT, wkeT, wveT, pbq, bke, bve, qbuf, kvbuf16, N);

  // layer 0 edge attention
  k_edge<<<(N + 3) / 4, 256, 0, stream>>>(qbuf, kvbuf16, rowptr, deg,
                                          csr_src, ppr, agg16, N);

  // fused: gate-l0 (residual from x) + qkv-l1 (A from LDS)
  k_gate_qkv<<<mfmaBlocks, 256, 0, stream>>>(
      agg16, waT, pba, d_in[0], hbuf, pskip, flags,
      wqT + (size_t)CD * CD, wkeT + (size_t)CD * CD, wveT + (size_t)CD * CD,
      pbq + CD, bke + CD, bve + CD, qbuf, kvbuf16, N);

  // layer 1 edge attention
  k_edge<<<(N + 3) / 4, 256, 0, stream>>>(qbuf, kvbuf16, rowptr, deg,
                                          csr_src, ppr + HH, agg16, N);

  // layer 1 gate + fused final projection
  k_gemm_gate<<<mfmaBlocks, 256, 0, stream>>>(
      agg16, waT + (size_t)CD * CD, pba + CD, hbuf, pskip + 1,
      pWfc, pbfc, d_out, flags, N);
}

// Round 9
// 773.804 us; speedup vs baseline: 1.0181x; 1.0181x over previous
//
#include <hip/hip_runtime.h>
#include <hip/hip_bf16.h>
#include <math.h>

#define CD 128
#define HH 4
#define DH 32
#define LL 2

using bf16 = __hip_bfloat16;
using bf16x8 = __attribute__((ext_vector_type(8))) short;  // 8 bf16 (4 VGPRs)
using f32x4 = __attribute__((ext_vector_type(4))) float;

__device__ __forceinline__ float bfbits2f(unsigned int s) {
  return __uint_as_float(s << 16);
}

__device__ __forceinline__ unsigned short f2bfbits(float f) {
  unsigned int u = __float_as_uint(f);
  unsigned int r = (u + 0x7fff + ((u >> 16) & 1)) >> 16;  // RNE
  return (unsigned short)r;
}

__device__ __forceinline__ float gelu_f(float x) {
  return 0.5f * x * (1.0f + erff(x * 0.70710678118654752f));
}

// ---- detect input formats: flags[0]=floats-are-f32, flags[1]=edge-index-is-i64 ----
__global__ void k_detect(const void* __restrict__ x, const int* __restrict__ ei,
                         int* __restrict__ flags) {
  __shared__ int cnt_f32, cnt_i32;
  if (threadIdx.x == 0) { cnt_f32 = 0; cnt_i32 = 0; }
  __syncthreads();
  int t = threadIdx.x;  // 128 threads
  unsigned short u = ((const unsigned short*)x)[2 * t];
  float v = bfbits2f((unsigned int)u);
  float av = fabsf(v);
  if (av != 0.f && (av > 1e8f || av < 1e-8f)) atomicAdd(&cnt_f32, 1);
  if (t < 64) {
    if (((const int*)ei)[2 * t + 1] != 0) atomicAdd(&cnt_i32, 1);
  }
  __syncthreads();
  if (threadIdx.x == 0) {
    flags[0] = (cnt_f32 > 8) ? 1 : 0;
    flags[1] = (cnt_i32 == 0) ? 1 : 0;
  }
}

#define NSEG 14
struct SegTab {
  const void* src[NSEG];
  int off[NSEG];
  int total;
};

__device__ __forceinline__ int edge_idx(const int* __restrict__ ei, long pos, int is64) {
  return is64 ? ei[2 * pos] : ei[pos];
}

#define BTILE 4096

// ==== FUSED pre-pass: {cvt_params, histb} (r5) ====
__global__ __launch_bounds__(256) void k_pre(
    SegTab tab, float* __restrict__ pdst,
    const int* __restrict__ ei, int* __restrict__ deg, int* __restrict__ bcnt,
    int E, int Nn, int shift, const int* __restrict__ flags, int parB) {
  __shared__ int cnt[256];
  const int bx = blockIdx.x;
  if (bx < parB) {
    int i = bx * 256 + threadIdx.x;
    if (i >= tab.total) return;
    int seg = 0;
#pragma unroll
    for (int k = 1; k < NSEG; k++)
      if (i >= tab.off[k]) seg = k;
    int j = i - tab.off[seg];
    const void* src = tab.src[seg];
    pdst[i] = flags[0] ? ((const float*)src)[j]
                       : bfbits2f((unsigned int)((const unsigned short*)src)[j]);
  } else {
    cnt[threadIdx.x] = 0;
    __syncthreads();
    const int t0 = (bx - parB) * BTILE;
    const int is64 = flags[1];
    for (int j = 0; j < 16; j++) {
      int i = t0 + threadIdx.x + j * 256;
      if (i < E) {
        int d = edge_idx(ei, (long)E + i, is64);
        if ((unsigned)d >= (unsigned)Nn) d = 0;
        atomicAdd(&deg[d], 1);
        atomicAdd(&cnt[d >> shift], 1);
      }
    }
    __syncthreads();
    int v = cnt[threadIdx.x];
    if (v > 0) atomicAdd(&bcnt[threadIdx.x], v);
  }
}

// ==== FUSED stage 2: {eff, wt, scan1} (r4, unchanged) ====
__global__ __launch_bounds__(256) void k_w1(
    const float* __restrict__ pWk, const float* __restrict__ pbk,
    const float* __restrict__ pWv, const float* __restrict__ pbv,
    const float* __restrict__ par, const float* __restrict__ pmr,
    unsigned short* __restrict__ wkeT, float* __restrict__ bke,
    unsigned short* __restrict__ wveT, float* __restrict__ bve,
    const float* __restrict__ pWq, const float* __restrict__ pWa,
    unsigned short* __restrict__ wqT, unsigned short* __restrict__ waT,
    const int* __restrict__ deg, int* __restrict__ tmp, int* __restrict__ bsum,
    int n, int effB, int wtB) {
  __shared__ int sh[256];
  const int bx = blockIdx.x;
  if (bx < effB) {
    int i = bx * 256 + threadIdx.x;
    const int total = LL * 2 * (CD + 1) * HH * DH;
    if (i >= total) return;
    int e = i & 31;
    int h = (i >> 5) & 3;
    int c = (i >> 7) % (CD + 1);
    int z = (i >> 7) / (CD + 1);
    int l = z >> 1, which = z & 1;
    const float* W = (which ? pWv : pWk) + (size_t)l * CD * CD;
    const float* B = (which ? pbv : pbk) + (size_t)l * CD;
    const float* R = (which ? pmr : par) + (size_t)l * HH * DH * DH + h * DH * DH;
    unsigned short* WoT = (which ? wveT : wkeT) + (size_t)l * CD * CD;
    float* Bo = (which ? bve : bke) + (size_t)l * CD;
    float acc = 0.f;
    if (c < CD) {
#pragma unroll
      for (int d = 0; d < DH; d++) acc += W[c * CD + h * DH + d] * R[d * DH + e];
      WoT[(size_t)(h * DH + e) * CD + c] = f2bfbits(acc);
    } else {
#pragma unroll
      for (int d = 0; d < DH; d++) acc += B[h * DH + d] * R[d * DH + e];
      Bo[h * DH + e] = acc;
    }
  } else if (bx < effB + wtB) {
    int i = (bx - effB) * 256 + threadIdx.x;  // < LL*2*CD*CD exactly
    int cin = i & 127;
    int cout = (i >> 7) & 127;
    int z = i >> 14;
    int l = z >> 1, which = z & 1;
    const float* W = (which ? pWa : pWq) + (size_t)l * CD * CD;
    unsigned short* WT = (which ? waT : wqT) + (size_t)l * CD * CD;
    WT[(size_t)cout * CD + cin] = f2bfbits(W[(size_t)cin * CD + cout]);
  } else {
    const int b = bx - effB - wtB;
    int i = b * 256 + threadIdx.x;
    int v = (i < n) ? deg[i] : 0;
    sh[threadIdx.x] = v;
    __syncthreads();
    for (int off = 1; off < 256; off <<= 1) {
      int t = (threadIdx.x >= off) ? sh[threadIdx.x - off] : 0;
      __syncthreads();
      sh[threadIdx.x] += t;
      __syncthreads();
    }
    if (i < n) tmp[i] = sh[threadIdx.x];
    if (threadIdx.x == 255) bsum[b] = sh[255];
  }
}

// ==== FUSED stage 3: {scan2, bscan} (r4, unchanged) ====
__global__ __launch_bounds__(256) void k_s2(
    int* __restrict__ bsum, int nb, const int* __restrict__ bcnt,
    int* __restrict__ bbase, int* __restrict__ bfill) {
  __shared__ int sh[256];
  __shared__ int carry;
  if (blockIdx.x == 0) {
    if (threadIdx.x == 0) carry = 0;
    __syncthreads();
    for (int base = 0; base < nb; base += 256) {
      int i = base + threadIdx.x;
      int v = (i < nb) ? bsum[i] : 0;
      sh[threadIdx.x] = v;
      __syncthreads();
      for (int off = 1; off < 256; off <<= 1) {
        int t = (threadIdx.x >= off) ? sh[threadIdx.x - off] : 0;
        __syncthreads();
        sh[threadIdx.x] += t;
        __syncthreads();
      }
      if (i < nb) bsum[i] = sh[threadIdx.x] + carry;
      __syncthreads();
      if (threadIdx.x == 0) carry += sh[255];
      __syncthreads();
    }
  } else {
    int t = threadIdx.x;
    int v = bcnt[t];
    sh[t] = v;
    __syncthreads();
    for (int off = 1; off < 256; off <<= 1) {
      int u = (t >= off) ? sh[t - off] : 0;
      __syncthreads();
      sh[t] += u;
      __syncthreads();
    }
    int excl = sh[t] - v;
    bbase[t] = excl;
    bfill[t] = excl;
  }
}

// ==== FUSED stage 4: {scan3, bin} (r4, unchanged) ====
__global__ __launch_bounds__(256) void k_s3bin(
    const int* __restrict__ tmp, const int* __restrict__ deg,
    const int* __restrict__ bsum, int* __restrict__ rowptr,
    int* __restrict__ fill, int n, int nB,
    const int* __restrict__ ei, int* __restrict__ bfill,
    int* __restrict__ ebs, int* __restrict__ ebd,
    const int* __restrict__ flags, int E, int Nn, int shift) {
  __shared__ int sS[BTILE];
  __shared__ int sD[BTILE];
  __shared__ int cnt[256], pref[256], base[256], lofs[256];
  const int bx = blockIdx.x;
  if (bx < nB) {
    int i = bx * 256 + threadIdx.x;
    if (i >= n) return;
    int off = (bx > 0) ? bsum[bx - 1] : 0;
    int excl = tmp[i] - deg[i] + off;
    rowptr[i] = excl;
    fill[i] = excl;
    return;
  }
  const int t = threadIdx.x;
  cnt[t] = 0;
  lofs[t] = 0;
  __syncthreads();
  const int t0 = (bx - nB) * BTILE;
  const int is64 = flags[1];
  for (int j = 0; j < 16; j++) {
    int i = t0 + t + j * 256;
    if (i < E) {
      int d = edge_idx(ei, (long)E + i, is64);
      if ((unsigned)d >= (unsigned)Nn) d = 0;
      atomicAdd(&cnt[d >> shift], 1);
    }
  }
  __syncthreads();
  {
    int v = cnt[t];
    pref[t] = v;
    __syncthreads();
    for (int off = 1; off < 256; off <<= 1) {
      int u = (t >= off) ? pref[t - off] : 0;
      __syncthreads();
      pref[t] += u;
      __syncthreads();
    }
    int incl = pref[t];
    __syncthreads();
    pref[t] = incl - v;
    base[t] = (v > 0) ? atomicAdd(&bfill[t], v) : 0;
  }
  __syncthreads();
  for (int j = 0; j < 16; j++) {
    int i = t0 + t + j * 256;
    if (i < E) {
      int s = edge_idx(ei, (long)i, is64);
      int d = edge_idx(ei, (long)E + i, is64);
      if ((unsigned)s >= (unsigned)Nn) s = 0;
      if ((unsigned)d >= (unsigned)Nn) d = 0;
      int b = d >> shift;
      int p = pref[b] + atomicAdd(&lofs[b], 1);
      sS[p] = s;
      sD[p] = d;
    }
  }
  __syncthreads();
  int tot = E - t0;
  if (tot > BTILE) tot = BTILE;
  for (int j = 0; j < 16; j++) {
    int i = t + j * 256;
    if (i < tot) {
      int d = sD[i];
      int b = d >> shift;
      int gp = base[b] + (i - pref[b]);
      ebs[gp] = sS[i];
      ebd[gp] = d;
    }
  }
}

// final scatter within per-bucket csr window (L2-local)
__global__ void k_scatter2(const int* __restrict__ bbase, const int* __restrict__ bcnt,
                           const int* __restrict__ ebs, const int* __restrict__ ebd,
                           int* __restrict__ fill, int* __restrict__ csr_src) {
  int b = blockIdx.x >> 1, half = blockIdx.x & 1;
  int s0 = bbase[b], c = bcnt[b];
  int st = s0 + (half ? (c + 1) / 2 : 0);
  int en = s0 + (half ? c : (c + 1) / 2);
  for (int i = st + threadIdx.x; i < en; i += 256) {
    int s = ebs[i], d = ebd[i];
    int pos = atomicAdd(&fill[d], 1);
    csr_src[pos] = s;
  }
}

// ==== fused q/k/v MFMA GEMM for layer 0, reading raw x.
// r9: __launch_bounds__(256,4) caps unified VGPR+AGPR at 128 -> >=4 waves/SIMD
// (occupancy-bracket arithmetic: total regs >128 drops to 2 waves/SIMD). ====
__global__ __launch_bounds__(256, 4) void k_gemm_qkv(
    const void* __restrict__ Araw, int a_is_x, const int* __restrict__ flags,
    const unsigned short* __restrict__ wq, const unsigned short* __restrict__ wk,
    const unsigned short* __restrict__ wv,
    const float* __restrict__ bq, const float* __restrict__ bk,
    const float* __restrict__ bv,
    float* __restrict__ qout, unsigned short* __restrict__ kvout, int nrows) {
  const int which = blockIdx.y;
  const unsigned short* BT = (which == 0) ? wq : (which == 1) ? wk : wv;
  const float* bias = (which == 0) ? bq : (which == 1) ? bk : bv;
  const int w = threadIdx.x >> 6;
  const int l = threadIdx.x & 63;
  const int r0 = blockIdx.x * 64 + w * 16;
  if (r0 >= nrows) return;
  const int lrow = l & 15;
  const int quad = l >> 4;
  const int k0 = quad * 8;
  const int ax_f32 = a_is_x ? flags[0] : 0;

  f32x4 acc[8];
#pragma unroll
  for (int ct = 0; ct < 8; ct++) {
    float b = bias[ct * 16 + lrow];
    acc[ct] = (f32x4){b, b, b, b};
  }
  int ar = r0 + lrow;
  if (ar >= nrows) ar = nrows - 1;
#pragma unroll
  for (int kc = 0; kc < 4; kc++) {
    bf16x8 af;
    if (ax_f32) {
      const float* Af = (const float*)Araw + (size_t)ar * CD + kc * 32 + k0;
      float4 a = *(const float4*)Af;
      float4 b = *(const float4*)(Af + 4);
      af[0] = (short)f2bfbits(a.x); af[1] = (short)f2bfbits(a.y);
      af[2] = (short)f2bfbits(a.z); af[3] = (short)f2bfbits(a.w);
      af[4] = (short)f2bfbits(b.x); af[5] = (short)f2bfbits(b.y);
      af[6] = (short)f2bfbits(b.z); af[7] = (short)f2bfbits(b.w);
    } else {
      af = *(const bf16x8*)((const unsigned short*)Araw + (size_t)ar * CD + kc * 32 + k0);
    }
#pragma unroll
    for (int ct = 0; ct < 8; ct++) {
      bf16x8 bfr = *(const bf16x8*)(BT + (size_t)(ct * 16 + lrow) * CD + kc * 32 + k0);
      acc[ct] = __builtin_amdgcn_mfma_f32_16x16x32_bf16(af, bfr, acc[ct], 0, 0, 0);
    }
  }
#pragma unroll
  for (int ct = 0; ct < 8; ct++) {
#pragma unroll
    for (int i = 0; i < 4; i++) {
      int gr = r0 + quad * 4 + i;
      if (gr >= nrows) continue;
      int col = ct * 16 + lrow;
      float val = acc[ct][i];
      if (which == 0) {
        qout[(size_t)gr * CD + col] = val;
      } else {
        unsigned short* o = kvout + ((size_t)gr << 8) + ((which == 2) ? CD : 0);
        o[col] = f2bfbits(val);
      }
    }
  }
}

// ==== FUSED gate-l0 + qkv-l1 (r9 occupancy fix):
// r8 PM: VGPR_Count=72 is arch-VGPRs only; phase-1 acc (32 AGPR) + phase-2 acc
// (32 AGPR) don't share across the barrier -> unified total ~136 > 128 ->
// HARD 2 waves/SIMD = 25% (measured 27%). All pipes idle (VALU 7.6%).
// Fix: __launch_bounds__(256,4) caps unified regs at 128 (forces allocator to
// share the accumulator across phases; minimal live set ~70 regs, no spill);
// afr hoist reverted (af loaded per-kc from LDS, 4 regs live not 16).
// Math bit-identical. ====
__global__ __launch_bounds__(256, 4) void k_gate_qkv(
    const unsigned short* __restrict__ A, const unsigned short* __restrict__ BTa,
    const float* __restrict__ ba, const void* __restrict__ xres,
    float* __restrict__ h, const float* __restrict__ skip,
    const int* __restrict__ flags,
    const unsigned short* __restrict__ wq1, const unsigned short* __restrict__ wk1,
    const unsigned short* __restrict__ wv1,
    const float* __restrict__ bq1, const float* __restrict__ bk1,
    const float* __restrict__ bv1,
    float* __restrict__ qout, unsigned short* __restrict__ kvout, int nrows) {
  __shared__ unsigned short sA[64][136];
  const int w = threadIdx.x >> 6;
  const int l = threadIdx.x & 63;
  const int blkbase = blockIdx.x * 64;
  const int r0 = blkbase + w * 16;
  const int lrow = l & 15;
  const int quad = l >> 4;
  const int k0 = quad * 8;
  const int xf32 = flags[0];

  // ---- phase 1: gate for this wave's 16 rows ----
  if (r0 < nrows) {
    f32x4 acc[8];
#pragma unroll
    for (int ct = 0; ct < 8; ct++) {
      float b = ba[ct * 16 + lrow];
      acc[ct] = (f32x4){b, b, b, b};
    }
    int ar = r0 + lrow;
    if (ar >= nrows) ar = nrows - 1;
    const unsigned short* Ap = A + (size_t)ar * CD;
#pragma unroll
    for (int kc = 0; kc < 4; kc++) {
      bf16x8 af = *(const bf16x8*)(Ap + kc * 32 + k0);
#pragma unroll
      for (int ct = 0; ct < 8; ct++) {
        bf16x8 bfr = *(const bf16x8*)(BTa + (size_t)(ct * 16 + lrow) * CD + kc * 32 + k0);
        acc[ct] = __builtin_amdgcn_mfma_f32_16x16x32_bf16(af, bfr, acc[ct], 0, 0, 0);
      }
    }
    float gg = 1.f / (1.f + __expf(-skip[0]));
#pragma unroll
    for (int ct = 0; ct < 8; ct++) {
#pragma unroll
      for (int i = 0; i < 4; i++) {
        int gr = r0 + quad * 4 + i;
        if (gr >= nrows) continue;
        size_t ix = (size_t)gr * CD + ct * 16 + lrow;
        float hres = xf32 ? ((const float*)xres)[ix]
                          : bfbits2f((unsigned int)((const unsigned short*)xres)[ix]);
        float o = gg * acc[ct][i] + (1.f - gg) * hres;
        h[ix] = o;
        sA[gr - blkbase][ct * 16 + lrow] = f2bfbits(o);
      }
    }
  }
  __syncthreads();
  if (r0 >= nrows) return;

  // ---- phase 2: qkv-l1 from LDS; projections SEQUENTIAL, af per-kc ----
  int ar = r0 + lrow;
  if (ar >= nrows) ar = nrows - 1;
  const unsigned short* Alds = &sA[ar - blkbase][0];
#pragma unroll 1
  for (int which = 0; which < 3; which++) {
    const unsigned short* BT = (which == 0) ? wq1 : (which == 1) ? wk1 : wv1;
    const float* bias = (which == 0) ? bq1 : (which == 1) ? bk1 : bv1;
    f32x4 acc[8];
#pragma unroll
    for (int ct = 0; ct < 8; ct++) {
      float b = bias[ct * 16 + lrow];
      acc[ct] = (f32x4){b, b, b, b};
    }
#pragma unroll
    for (int kc = 0; kc < 4; kc++) {
      bf16x8 af = *(const bf16x8*)(Alds + kc * 32 + k0);
#pragma unroll
      for (int ct = 0; ct < 8; ct++) {
        bf16x8 bfr = *(const bf16x8*)(BT + (size_t)(ct * 16 + lrow) * CD + kc * 32 + k0);
        acc[ct] = __builtin_amdgcn_mfma_f32_16x16x32_bf16(af, bfr, acc[ct], 0, 0, 0);
      }
    }
#pragma unroll
    for (int ct = 0; ct < 8; ct++) {
#pragma unroll
      for (int i = 0; i < 4; i++) {
        int gr = r0 + quad * 4 + i;
        if (gr >= nrows) continue;
        int col = ct * 16 + lrow;
        float val = acc[ct][i];
        if (which == 0) {
          qout[(size_t)gr * CD + col] = val;
        } else {
          unsigned short* o = kvout + ((size_t)gr << 8) + ((which == 2) ? CD : 0);
          o[col] = f2bfbits(val);
        }
      }
    }
  }
}

// ==== gate MFMA GEMM, FINAL layer only: gelu(agg)@Wa + ba, gated residual
// from h f32, fused 128x2 output projection. r9: +launch_bounds(256,4). ====
__global__ __launch_bounds__(256, 4) void k_gemm_gate(
    const unsigned short* __restrict__ A, const unsigned short* __restrict__ BT,
    const float* __restrict__ bias, const float* __restrict__ h,
    const float* __restrict__ skip,
    const float* __restrict__ Wfc, const float* __restrict__ bfc,
    void* __restrict__ out, const int* __restrict__ flags, int nrows) {
  const int w = threadIdx.x >> 6;
  const int l = threadIdx.x & 63;
  const int r0 = blockIdx.x * 64 + w * 16;
  if (r0 >= nrows) return;
  const int lrow = l & 15;
  const int quad = l >> 4;
  const int k0 = quad * 8;
  const int xf32 = flags[0];

  f32x4 acc[8];
#pragma unroll
  for (int ct = 0; ct < 8; ct++) {
    float b = bias[ct * 16 + lrow];
    acc[ct] = (f32x4){b, b, b, b};
  }
  int ar = r0 + lrow;
  if (ar >= nrows) ar = nrows - 1;
  const unsigned short* Ap = A + (size_t)ar * CD;
#pragma unroll
  for (int kc = 0; kc < 4; kc++) {
    bf16x8 af = *(const bf16x8*)(Ap + kc * 32 + k0);
#pragma unroll
    for (int ct = 0; ct < 8; ct++) {
      bf16x8 bfr = *(const bf16x8*)(BT + (size_t)(ct * 16 + lrow) * CD + kc * 32 + k0);
      acc[ct] = __builtin_amdgcn_mfma_f32_16x16x32_bf16(af, bfr, acc[ct], 0, 0, 0);
    }
  }
  float gg = 1.f / (1.f + __expf(-skip[0]));
  float p0[4] = {0.f, 0.f, 0.f, 0.f};
  float p1[4] = {0.f, 0.f, 0.f, 0.f};
#pragma unroll
  for (int ct = 0; ct < 8; ct++) {
    float w0 = Wfc[(ct * 16 + lrow) * 2];
    float w1 = Wfc[(ct * 16 + lrow) * 2 + 1];
#pragma unroll
    for (int i = 0; i < 4; i++) {
      int gr = r0 + quad * 4 + i;
      if (gr >= nrows) continue;
      size_t ix = (size_t)gr * CD + ct * 16 + lrow;
      float o = gg * acc[ct][i] + (1.f - gg) * h[ix];
      p0[i] += o * w0;
      p1[i] += o * w1;
    }
  }
#pragma unroll
  for (int off = 1; off <= 8; off <<= 1) {
#pragma unroll
    for (int i = 0; i < 4; i++) {
      p0[i] += __shfl_xor(p0[i], off);
      p1[i] += __shfl_xor(p1[i], off);
    }
  }
  if (lrow == 0) {
#pragma unroll
    for (int i = 0; i < 4; i++) {
      int gr = r0 + quad * 4 + i;
      if (gr >= nrows) continue;
      float o0 = p0[i] + bfc[0];
      float o1 = p1[i] + bfc[1];
      if (xf32) {
        ((float*)out)[(size_t)gr * 2] = o0;
        ((float*)out)[(size_t)gr * 2 + 1] = o1;
      } else {
        ((bf16*)out)[(size_t)gr * 2] = __float2bfloat16(o0);
        ((bf16*)out)[(size_t)gr * 2 + 1] = __float2bfloat16(o1);
      }
    }
  }
}

// ---- per-edge compute: unpack k/v, dot with q, exp, accumulate ----
__device__ __forceinline__ void edge_acc(uint4 ku, uint4 vu, float4 qa, float4 qb,
                                         float* __restrict__ acc, float& den) {
  float k0 = bfbits2f(ku.x & 0xffffu), k1 = bfbits2f(ku.x >> 16);
  float k2 = bfbits2f(ku.y & 0xffffu), k3 = bfbits2f(ku.y >> 16);
  float k4 = bfbits2f(ku.z & 0xffffu), k5 = bfbits2f(ku.z >> 16);
  float k6 = bfbits2f(ku.w & 0xffffu), k7 = bfbits2f(ku.w >> 16);
  float v0 = bfbits2f(vu.x & 0xffffu), v1 = bfbits2f(vu.x >> 16);
  float v2 = bfbits2f(vu.y & 0xffffu), v3 = bfbits2f(vu.y >> 16);
  float v4 = bfbits2f(vu.z & 0xffffu), v5 = bfbits2f(vu.z >> 16);
  float v6 = bfbits2f(vu.w & 0xffffu), v7 = bfbits2f(vu.w >> 16);
  float pd = qa.x * k0 + qa.y * k1 + qa.z * k2 + qa.w * k3 +
             qb.x * k4 + qb.y * k5 + qb.z * k6 + qb.w * k7;
  pd += __shfl_xor(pd, 1);
  pd += __shfl_xor(pd, 2);
  float ew = __expf(fminf(pd, 60.f));  // no max-sub: |logit| ~ O(1), safe
  acc[0] += ew * v0; acc[1] += ew * v1;
  acc[2] += ew * v2; acc[3] += ew * v3;
  acc[4] += ew * v4; acc[5] += ew * v5;
  acc[6] += ew * v6; acc[7] += ew * v7;
  den += ew;
}

// ==== fused attention (unchanged; pinned at the random-256B-gather
// throughput ceiling ~3.75 TB/s across 3 schedules / occupancies 67-77%). ====
__global__ __launch_bounds__(256) void k_edge(
    const float* __restrict__ q, const unsigned short* __restrict__ kv,
    const int* __restrict__ rowptr, const int* __restrict__ deg,
    const int* __restrict__ csr_src, const float* __restrict__ p_rel,
    unsigned short* __restrict__ agg16, int N) {
  int n = (blockIdx.x * 256 + threadIdx.x) >> 6;
  if (n >= N) return;
  const int lane = threadIdx.x & 63;
  const int g = lane >> 4;
  const int j = lane & 15;
  const int start = rowptr[n];
  const int end = start + deg[n];
  const float prl = p_rel[j >> 2] * 0.17677669529663687f;  // 1/sqrt(32)
  float4 qa = *(const float4*)(q + (size_t)n * CD + 8 * j);
  float4 qb = *(const float4*)(q + (size_t)n * CD + 8 * j + 4);
  qa.x *= prl; qa.y *= prl; qa.z *= prl; qa.w *= prl;
  qb.x *= prl; qb.y *= prl; qb.z *= prl; qb.w *= prl;
  float den = 0.f;
  float acc[8] = {0.f, 0.f, 0.f, 0.f, 0.f, 0.f, 0.f, 0.f};
  int e = start + g;
  if (e < end) {
    const int last = end - 1;
    bool bok = (e + 4) < end;
    int sa = csr_src[e];
    int sb = csr_src[bok ? e + 4 : e];
    const unsigned short* pa = kv + ((size_t)sa << 8) + 8 * j;
    const unsigned short* pb = kv + ((size_t)sb << 8) + 8 * j;
    uint4 kua = *(const uint4*)pa;
    uint4 vua = *(const uint4*)(pa + CD);
    uint4 kub = *(const uint4*)pb;
    uint4 vub = *(const uint4*)(pb + CD);
    for (;;) {
      const int en = e + 8;
      int ea2 = (en < last) ? en : last;
      int eb2 = (en + 4 < last) ? en + 4 : last;
      int sa2 = csr_src[ea2];
      int sb2 = csr_src[eb2];
      const unsigned short* pa2 = kv + ((size_t)sa2 << 8) + 8 * j;
      const unsigned short* pb2 = kv + ((size_t)sb2 << 8) + 8 * j;
      uint4 kua2 = *(const uint4*)pa2;
      uint4 vua2 = *(const uint4*)(pa2 + CD);
      uint4 kub2 = *(const uint4*)pb2;
      uint4 vub2 = *(const uint4*)(pb2 + CD);
      __builtin_amdgcn_sched_barrier(0);
      edge_acc(kua, vua, qa, qb, acc, den);
      if (bok) edge_acc(kub, vub, qa, qb, acc, den);
      if (en >= end) break;
      e = en;
      bok = (en + 4) < end;
      kua = kua2; vua = vua2; kub = kub2; vub = vub2;
    }
  }
#pragma unroll
  for (int off = 16; off <= 32; off <<= 1) {
    den += __shfl_xor(den, off);
#pragma unroll
    for (int i = 0; i < 8; i++) acc[i] += __shfl_xor(acc[i], off);
  }
  if (g == 0) {
    float inv = (den > 0.f) ? 1.f / den : 0.f;
    ushort4 o0, o1;
    o0.x = f2bfbits(gelu_f(acc[0] * inv)); o0.y = f2bfbits(gelu_f(acc[1] * inv));
    o0.z = f2bfbits(gelu_f(acc[2] * inv)); o0.w = f2bfbits(gelu_f(acc[3] * inv));
    o1.x = f2bfbits(gelu_f(acc[4] * inv)); o1.y = f2bfbits(gelu_f(acc[5] * inv));
    o1.z = f2bfbits(gelu_f(acc[6] * inv)); o1.w = f2bfbits(gelu_f(acc[7] * inv));
    *(ushort4*)(agg16 + (size_t)n * CD + 8 * j) = o0;
    *(ushort4*)(agg16 + (size_t)n * CD + 8 * j + 4) = o1;
  }
}

extern "C" void kernel_launch(void* const* d_in, const int* in_sizes, int n_in,
                              void* d_out, int out_size, void* d_ws, size_t ws_size,
                              hipStream_t stream) {
  const int* ei = (const int*)d_in[1];
  const int N = in_sizes[0] / CD;
  const int E = in_sizes[1] / 2;
  const size_t NC = (size_t)N * CD;
  const int nB = (N + 255) / 256;
  int shift = 0;
  while (((N - 1) >> shift) >= 256) shift++;  // 256 coarse buckets

  float* p = (float*)d_ws;
  float* hbuf = p;                                    // NC f32 (h1 storage)
  float* qbuf = p + NC;                               // NC f32
  float* cur = p + 2 * NC;
  unsigned short* kvbuf16 = (unsigned short*)cur; cur += NC;  // N x 256 bf16 (k|v)
  unsigned short* agg16 = (unsigned short*)cur; cur += NC / 2;
  int* ip = (int*)cur;
  int* deg = ip;
  int* tmp = ip + N;
  int* rowptr = ip + 2 * N;
  int* fill = ip + 3 * N;
  int* bsum = ip + 4 * N;
  int* csr_src = ip + 4 * N + nB;
  int* bcnt = csr_src + E;     // 256
  int* bbase = bcnt + 256;     // 256
  int* bfill = bbase + 256;    // 256
  cur = (float*)(bfill + 256);
  unsigned short* wkeT = (unsigned short*)cur; cur += (size_t)LL * CD * CD / 2;
  unsigned short* wveT = (unsigned short*)cur; cur += (size_t)LL * CD * CD / 2;
  unsigned short* wqT = (unsigned short*)cur; cur += (size_t)LL * CD * CD / 2;
  unsigned short* waT = (unsigned short*)cur; cur += (size_t)LL * CD * CD / 2;
  float* bke = cur; cur += (size_t)LL * CD;
  float* bve = cur; cur += (size_t)LL * CD;
  float* pblock = cur;
  float* pWk = cur; cur += (size_t)LL * CD * CD;
  float* pbk = cur; cur += (size_t)LL * CD;
  float* pWq = cur; cur += (size_t)LL * CD * CD;
  float* pbq = cur; cur += (size_t)LL * CD;
  float* pWv = cur; cur += (size_t)LL * CD * CD;
  float* pbv = cur; cur += (size_t)LL * CD;
  float* par = cur; cur += (size_t)LL * HH * DH * DH;
  float* pmr = cur; cur += (size_t)LL * HH * DH * DH;
  float* ppr = cur; cur += (size_t)LL * HH;
  float* pWa = cur; cur += (size_t)LL * CD * CD;
  float* pba = cur; cur += (size_t)LL * CD;
  float* pskip = cur; cur += LL;
  float* pWfc = cur; cur += (size_t)CD * 2;
  float* pbfc = cur; cur += 2;
  int* flags = (int*)cur;

  // binned-edge staging aliases kvbuf16 (only used before layer loop)
  int* ebs = (int*)kvbuf16;      // E ints
  int* ebd = ebs + E;            // E ints

  SegTab tab;
  const int sizes[NSEG] = {LL * CD * CD, LL * CD, LL * CD * CD, LL * CD,
                           LL * CD * CD, LL * CD, LL * HH * DH * DH,
                           LL * HH * DH * DH, LL * HH, LL * CD * CD, LL * CD,
                           LL, CD * 2, 2};
  const int srcIdx[NSEG] = {2, 3, 4, 5, 6, 7, 8, 9, 10, 11, 12, 13, 14, 15};
  int off = 0;
  for (int k = 0; k < NSEG; k++) {
    tab.src[k] = d_in[srcIdx[k]];
    tab.off[k] = off;
    off += sizes[k];
  }
  tab.total = off;

  hipMemsetAsync(deg, 0, (size_t)N * sizeof(int), stream);
  hipMemsetAsync(bcnt, 0, 256 * sizeof(int), stream);
  k_detect<<<1, 128, 0, stream>>>(d_in[0], ei, flags);

  const int parB = (tab.total + 255) / 256;
  const int histB = (E + BTILE - 1) / BTILE;
  k_pre<<<parB + histB, 256, 0, stream>>>(tab, pblock, ei, deg, bcnt, E, N,
                                          shift, flags, parB);

  const int effB = (LL * 2 * (CD + 1) * HH * DH + 255) / 256;
  const int wtB = (LL * 2 * CD * CD) / 256;
  k_w1<<<effB + wtB + nB, 256, 0, stream>>>(
      pWk, pbk, pWv, pbv, par, pmr, wkeT, bke, wveT, bve,
      pWq, pWa, wqT, waT, deg, tmp, bsum, N, effB, wtB);

  k_s2<<<2, 256, 0, stream>>>(bsum, nB, bcnt, bbase, bfill);
  k_s3bin<<<nB + histB, 256, 0, stream>>>(tmp, deg, bsum, rowptr, fill, N, nB,
                                          ei, bfill, ebs, ebd, flags, E, N, shift);
  k_scatter2<<<512, 256, 0, stream>>>(bbase, bcnt, ebs, ebd, fill, csr_src);

  const int mfmaBlocks = (N + 63) / 64;

  // layer 0 qkv (from raw x)
  k_gemm_qkv<<<dim3(mfmaBlocks, 3), 256, 0, stream>>>(
      d_in[0], 1, flags, wqT, wkeT, wveT, pbq, bke, bve, qbuf, kvbuf16, N);

  // layer 0 edge attention
  k_edge<<<(N + 3) / 4, 256, 0, stream>>>(qbuf, kvbuf16, rowptr, deg,
                                          csr_src, ppr, agg16, N);

  // fused: gate-l0 (residual from x) + qkv-l1 (A from LDS)
  k_gate_qkv<<<mfmaBlocks, 256, 0, stream>>>(
      agg16, waT, pba, d_in[0], hbuf, pskip, flags,
      wqT + (size_t)CD * CD, wkeT + (size_t)CD * CD, wveT + (size_t)CD * CD,
      pbq + CD, bke + CD, bve + CD, qbuf, kvbuf16, N);

  // layer 1 edge attention
  k_edge<<<(N + 3) / 4, 256, 0, stream>>>(qbuf, kvbuf16, rowptr, deg,
                                          csr_src, ppr + HH, agg16, N);

  // layer 1 gate + fused final projection
  k_gemm_gate<<<mfmaBlocks, 256, 0, stream>>>(
      agg16, waT + (size_t)CD * CD, pba + CD, hbuf, pskip + 1,
      pWfc, pbfc, d_out, flags, N);
}

// Round 10
// 722.979 us; speedup vs baseline: 1.0897x; 1.0703x over previous
//
#include <hip/hip_runtime.h>
#include <hip/hip_bf16.h>
#include <math.h>

#define CD 128
#define HH 4
#define DH 32
#define LL 2

using bf16 = __hip_bfloat16;
using bf16x8 = __attribute__((ext_vector_type(8))) short;  // 8 bf16 (4 VGPRs)
using f32x4 = __attribute__((ext_vector_type(4))) float;

__device__ __forceinline__ float bfbits2f(unsigned int s) {
  return __uint_as_float(s << 16);
}

__device__ __forceinline__ unsigned short f2bfbits(float f) {
  unsigned int u = __float_as_uint(f);
  unsigned int r = (u + 0x7fff + ((u >> 16) & 1)) >> 16;  // RNE
  return (unsigned short)r;
}

__device__ __forceinline__ float gelu_f(float x) {
  return 0.5f * x * (1.0f + erff(x * 0.70710678118654752f));
}

// ---- detect input formats: flags[0]=floats-are-f32, flags[1]=edge-index-is-i64 ----
__global__ void k_detect(const void* __restrict__ x, const int* __restrict__ ei,
                         int* __restrict__ flags) {
  __shared__ int cnt_f32, cnt_i32;
  if (threadIdx.x == 0) { cnt_f32 = 0; cnt_i32 = 0; }
  __syncthreads();
  int t = threadIdx.x;  // 128 threads
  unsigned short u = ((const unsigned short*)x)[2 * t];
  float v = bfbits2f((unsigned int)u);
  float av = fabsf(v);
  if (av != 0.f && (av > 1e8f || av < 1e-8f)) atomicAdd(&cnt_f32, 1);
  if (t < 64) {
    if (((const int*)ei)[2 * t + 1] != 0) atomicAdd(&cnt_i32, 1);
  }
  __syncthreads();
  if (threadIdx.x == 0) {
    flags[0] = (cnt_f32 > 8) ? 1 : 0;
    flags[1] = (cnt_i32 == 0) ? 1 : 0;
  }
}

#define NSEG 14
struct SegTab {
  const void* src[NSEG];
  int off[NSEG];
  int total;
};

__device__ __forceinline__ int edge_idx(const int* __restrict__ ei, long pos, int is64) {
  return is64 ? ei[2 * pos] : ei[pos];
}

#define BTILE 4096

// ==== FUSED pre-pass: {cvt_params, histb} (r5) ====
__global__ __launch_bounds__(256) void k_pre(
    SegTab tab, float* __restrict__ pdst,
    const int* __restrict__ ei, int* __restrict__ deg, int* __restrict__ bcnt,
    int E, int Nn, int shift, const int* __restrict__ flags, int parB) {
  __shared__ int cnt[256];
  const int bx = blockIdx.x;
  if (bx < parB) {
    int i = bx * 256 + threadIdx.x;
    if (i >= tab.total) return;
    int seg = 0;
#pragma unroll
    for (int k = 1; k < NSEG; k++)
      if (i >= tab.off[k]) seg = k;
    int j = i - tab.off[seg];
    const void* src = tab.src[seg];
    pdst[i] = flags[0] ? ((const float*)src)[j]
                       : bfbits2f((unsigned int)((const unsigned short*)src)[j]);
  } else {
    cnt[threadIdx.x] = 0;
    __syncthreads();
    const int t0 = (bx - parB) * BTILE;
    const int is64 = flags[1];
    for (int j = 0; j < 16; j++) {
      int i = t0 + threadIdx.x + j * 256;
      if (i < E) {
        int d = edge_idx(ei, (long)E + i, is64);
        if ((unsigned)d >= (unsigned)Nn) d = 0;
        atomicAdd(&deg[d], 1);
        atomicAdd(&cnt[d >> shift], 1);
      }
    }
    __syncthreads();
    int v = cnt[threadIdx.x];
    if (v > 0) atomicAdd(&bcnt[threadIdx.x], v);
  }
}

// ==== FUSED stage 2: {eff, wt, scan1} (r4, unchanged) ====
__global__ __launch_bounds__(256) void k_w1(
    const float* __restrict__ pWk, const float* __restrict__ pbk,
    const float* __restrict__ pWv, const float* __restrict__ pbv,
    const float* __restrict__ par, const float* __restrict__ pmr,
    unsigned short* __restrict__ wkeT, float* __restrict__ bke,
    unsigned short* __restrict__ wveT, float* __restrict__ bve,
    const float* __restrict__ pWq, const float* __restrict__ pWa,
    unsigned short* __restrict__ wqT, unsigned short* __restrict__ waT,
    const int* __restrict__ deg, int* __restrict__ tmp, int* __restrict__ bsum,
    int n, int effB, int wtB) {
  __shared__ int sh[256];
  const int bx = blockIdx.x;
  if (bx < effB) {
    int i = bx * 256 + threadIdx.x;
    const int total = LL * 2 * (CD + 1) * HH * DH;
    if (i >= total) return;
    int e = i & 31;
    int h = (i >> 5) & 3;
    int c = (i >> 7) % (CD + 1);
    int z = (i >> 7) / (CD + 1);
    int l = z >> 1, which = z & 1;
    const float* W = (which ? pWv : pWk) + (size_t)l * CD * CD;
    const float* B = (which ? pbv : pbk) + (size_t)l * CD;
    const float* R = (which ? pmr : par) + (size_t)l * HH * DH * DH + h * DH * DH;
    unsigned short* WoT = (which ? wveT : wkeT) + (size_t)l * CD * CD;
    float* Bo = (which ? bve : bke) + (size_t)l * CD;
    float acc = 0.f;
    if (c < CD) {
#pragma unroll
      for (int d = 0; d < DH; d++) acc += W[c * CD + h * DH + d] * R[d * DH + e];
      WoT[(size_t)(h * DH + e) * CD + c] = f2bfbits(acc);
    } else {
#pragma unroll
      for (int d = 0; d < DH; d++) acc += B[h * DH + d] * R[d * DH + e];
      Bo[h * DH + e] = acc;
    }
  } else if (bx < effB + wtB) {
    int i = (bx - effB) * 256 + threadIdx.x;  // < LL*2*CD*CD exactly
    int cin = i & 127;
    int cout = (i >> 7) & 127;
    int z = i >> 14;
    int l = z >> 1, which = z & 1;
    const float* W = (which ? pWa : pWq) + (size_t)l * CD * CD;
    unsigned short* WT = (which ? waT : wqT) + (size_t)l * CD * CD;
    WT[(size_t)cout * CD + cin] = f2bfbits(W[(size_t)cin * CD + cout]);
  } else {
    const int b = bx - effB - wtB;
    int i = b * 256 + threadIdx.x;
    int v = (i < n) ? deg[i] : 0;
    sh[threadIdx.x] = v;
    __syncthreads();
    for (int off = 1; off < 256; off <<= 1) {
      int t = (threadIdx.x >= off) ? sh[threadIdx.x - off] : 0;
      __syncthreads();
      sh[threadIdx.x] += t;
      __syncthreads();
    }
    if (i < n) tmp[i] = sh[threadIdx.x];
    if (threadIdx.x == 255) bsum[b] = sh[255];
  }
}

// ==== FUSED stage 3: {scan2, bscan} (r4, unchanged) ====
__global__ __launch_bounds__(256) void k_s2(
    int* __restrict__ bsum, int nb, const int* __restrict__ bcnt,
    int* __restrict__ bbase, int* __restrict__ bfill) {
  __shared__ int sh[256];
  __shared__ int carry;
  if (blockIdx.x == 0) {
    if (threadIdx.x == 0) carry = 0;
    __syncthreads();
    for (int base = 0; base < nb; base += 256) {
      int i = base + threadIdx.x;
      int v = (i < nb) ? bsum[i] : 0;
      sh[threadIdx.x] = v;
      __syncthreads();
      for (int off = 1; off < 256; off <<= 1) {
        int t = (threadIdx.x >= off) ? sh[threadIdx.x - off] : 0;
        __syncthreads();
        sh[threadIdx.x] += t;
        __syncthreads();
      }
      if (i < nb) bsum[i] = sh[threadIdx.x] + carry;
      __syncthreads();
      if (threadIdx.x == 0) carry += sh[255];
      __syncthreads();
    }
  } else {
    int t = threadIdx.x;
    int v = bcnt[t];
    sh[t] = v;
    __syncthreads();
    for (int off = 1; off < 256; off <<= 1) {
      int u = (t >= off) ? sh[t - off] : 0;
      __syncthreads();
      sh[t] += u;
      __syncthreads();
    }
    int excl = sh[t] - v;
    bbase[t] = excl;
    bfill[t] = excl;
  }
}

// ==== FUSED stage 4: {scan3, bin} (r4, unchanged) ====
__global__ __launch_bounds__(256) void k_s3bin(
    const int* __restrict__ tmp, const int* __restrict__ deg,
    const int* __restrict__ bsum, int* __restrict__ rowptr,
    int* __restrict__ fill, int n, int nB,
    const int* __restrict__ ei, int* __restrict__ bfill,
    int* __restrict__ ebs, int* __restrict__ ebd,
    const int* __restrict__ flags, int E, int Nn, int shift) {
  __shared__ int sS[BTILE];
  __shared__ int sD[BTILE];
  __shared__ int cnt[256], pref[256], base[256], lofs[256];
  const int bx = blockIdx.x;
  if (bx < nB) {
    int i = bx * 256 + threadIdx.x;
    if (i >= n) return;
    int off = (bx > 0) ? bsum[bx - 1] : 0;
    int excl = tmp[i] - deg[i] + off;
    rowptr[i] = excl;
    fill[i] = excl;
    return;
  }
  const int t = threadIdx.x;
  cnt[t] = 0;
  lofs[t] = 0;
  __syncthreads();
  const int t0 = (bx - nB) * BTILE;
  const int is64 = flags[1];
  for (int j = 0; j < 16; j++) {
    int i = t0 + t + j * 256;
    if (i < E) {
      int d = edge_idx(ei, (long)E + i, is64);
      if ((unsigned)d >= (unsigned)Nn) d = 0;
      atomicAdd(&cnt[d >> shift], 1);
    }
  }
  __syncthreads();
  {
    int v = cnt[t];
    pref[t] = v;
    __syncthreads();
    for (int off = 1; off < 256; off <<= 1) {
      int u = (t >= off) ? pref[t - off] : 0;
      __syncthreads();
      pref[t] += u;
      __syncthreads();
    }
    int incl = pref[t];
    __syncthreads();
    pref[t] = incl - v;
    base[t] = (v > 0) ? atomicAdd(&bfill[t], v) : 0;
  }
  __syncthreads();
  for (int j = 0; j < 16; j++) {
    int i = t0 + t + j * 256;
    if (i < E) {
      int s = edge_idx(ei, (long)i, is64);
      int d = edge_idx(ei, (long)E + i, is64);
      if ((unsigned)s >= (unsigned)Nn) s = 0;
      if ((unsigned)d >= (unsigned)Nn) d = 0;
      int b = d >> shift;
      int p = pref[b] + atomicAdd(&lofs[b], 1);
      sS[p] = s;
      sD[p] = d;
    }
  }
  __syncthreads();
  int tot = E - t0;
  if (tot > BTILE) tot = BTILE;
  for (int j = 0; j < 16; j++) {
    int i = t + j * 256;
    if (i < tot) {
      int d = sD[i];
      int b = d >> shift;
      int gp = base[b] + (i - pref[b]);
      ebs[gp] = sS[i];
      ebd[gp] = d;
    }
  }
}

// final scatter within per-bucket csr window (L2-local)
__global__ void k_scatter2(const int* __restrict__ bbase, const int* __restrict__ bcnt,
                           const int* __restrict__ ebs, const int* __restrict__ ebd,
                           int* __restrict__ fill, int* __restrict__ csr_src) {
  int b = blockIdx.x >> 1, half = blockIdx.x & 1;
  int s0 = bbase[b], c = bcnt[b];
  int st = s0 + (half ? (c + 1) / 2 : 0);
  int en = s0 + (half ? c : (c + 1) / 2);
  for (int i = st + threadIdx.x; i < en; i += 256) {
    int s = ebs[i], d = ebd[i];
    int pos = atomicAdd(&fill[d], 1);
    csr_src[pos] = s;
  }
}

// ==== fused q/k/v MFMA GEMM for layer 0, reading raw x (r9, unchanged). ====
__global__ __launch_bounds__(256, 4) void k_gemm_qkv(
    const void* __restrict__ Araw, int a_is_x, const int* __restrict__ flags,
    const unsigned short* __restrict__ wq, const unsigned short* __restrict__ wk,
    const unsigned short* __restrict__ wv,
    const float* __restrict__ bq, const float* __restrict__ bk,
    const float* __restrict__ bv,
    float* __restrict__ qout, unsigned short* __restrict__ kvout, int nrows) {
  const int which = blockIdx.y;
  const unsigned short* BT = (which == 0) ? wq : (which == 1) ? wk : wv;
  const float* bias = (which == 0) ? bq : (which == 1) ? bk : bv;
  const int w = threadIdx.x >> 6;
  const int l = threadIdx.x & 63;
  const int r0 = blockIdx.x * 64 + w * 16;
  if (r0 >= nrows) return;
  const int lrow = l & 15;
  const int quad = l >> 4;
  const int k0 = quad * 8;
  const int ax_f32 = a_is_x ? flags[0] : 0;

  f32x4 acc[8];
#pragma unroll
  for (int ct = 0; ct < 8; ct++) {
    float b = bias[ct * 16 + lrow];
    acc[ct] = (f32x4){b, b, b, b};
  }
  int ar = r0 + lrow;
  if (ar >= nrows) ar = nrows - 1;
#pragma unroll
  for (int kc = 0; kc < 4; kc++) {
    bf16x8 af;
    if (ax_f32) {
      const float* Af = (const float*)Araw + (size_t)ar * CD + kc * 32 + k0;
      float4 a = *(const float4*)Af;
      float4 b = *(const float4*)(Af + 4);
      af[0] = (short)f2bfbits(a.x); af[1] = (short)f2bfbits(a.y);
      af[2] = (short)f2bfbits(a.z); af[3] = (short)f2bfbits(a.w);
      af[4] = (short)f2bfbits(b.x); af[5] = (short)f2bfbits(b.y);
      af[6] = (short)f2bfbits(b.z); af[7] = (short)f2bfbits(b.w);
    } else {
      af = *(const bf16x8*)((const unsigned short*)Araw + (size_t)ar * CD + kc * 32 + k0);
    }
#pragma unroll
    for (int ct = 0; ct < 8; ct++) {
      bf16x8 bfr = *(const bf16x8*)(BT + (size_t)(ct * 16 + lrow) * CD + kc * 32 + k0);
      acc[ct] = __builtin_amdgcn_mfma_f32_16x16x32_bf16(af, bfr, acc[ct], 0, 0, 0);
    }
  }
#pragma unroll
  for (int ct = 0; ct < 8; ct++) {
#pragma unroll
    for (int i = 0; i < 4; i++) {
      int gr = r0 + quad * 4 + i;
      if (gr >= nrows) continue;
      int col = ct * 16 + lrow;
      float val = acc[ct][i];
      if (which == 0) {
        qout[(size_t)gr * CD + col] = val;
      } else {
        unsigned short* o = kvout + ((size_t)gr << 8) + ((which == 2) ? CD : 0);
        o[col] = f2bfbits(val);
      }
    }
  }
}

// ==== FUSED gate-l0 + qkv-l1 (r10: LDS weight staging):
// r9 PM: still 138us with all pipes idle — each wave streamed 4x32KB of
// weights from L2 (128 b128 loads x ~250cy latency/wave) and the 128-reg cap
// left no ILP room; loads serialized. Fix: stage the 128x128 weight matrix in
// LDS ONCE PER BLOCK (cooperative, XOR-swizzled: chunk^=row&15 on 16B chunks
// -> 16 lanes hit 16 distinct slots, min-aliasing b128 reads), re-staged per
// projection. MFMA loop reads LDS (~12cy) not L2 (~250cy). Barriers are
// OUTSIDE the act-guard (tail block's idle waves still reach them).
// LDS 17.4+32.8=50.2KB -> 3 blocks/CU; launch_bounds(256,3) relaxes the reg
// cap to ~170 (scheduler freedom). Data movement bit-identical. ====
__global__ __launch_bounds__(256, 3) void k_gate_qkv(
    const unsigned short* __restrict__ A, const unsigned short* __restrict__ BTa,
    const float* __restrict__ ba, const void* __restrict__ xres,
    float* __restrict__ h, const float* __restrict__ skip,
    const int* __restrict__ flags,
    const unsigned short* __restrict__ wq1, const unsigned short* __restrict__ wk1,
    const unsigned short* __restrict__ wv1,
    const float* __restrict__ bq1, const float* __restrict__ bk1,
    const float* __restrict__ bv1,
    float* __restrict__ qout, unsigned short* __restrict__ kvout, int nrows) {
  __shared__ unsigned short sA[64][136];
  __shared__ unsigned short sW[128 * 128];  // XOR-swizzled 16B chunks
  const int t = threadIdx.x;
  const int w = t >> 6;
  const int l = t & 63;
  const int blkbase = blockIdx.x * 64;
  const int r0 = blkbase + w * 16;
  const int lrow = l & 15;
  const int quad = l >> 4;
  const int k0 = quad * 8;
  const int xf32 = flags[0];
  const bool act = (r0 < nrows);
  const int srow = t >> 1;       // staging: thread pair per weight row
  const int shf = t & 1;         // which 64-col half

  // ---- stage Wa into sW (swizzled) ----
  {
    const unsigned short* src = BTa + (size_t)srow * CD + shf * 64;
#pragma unroll
    for (int j = 0; j < 8; j++) {
      int c = shf * 8 + j;
      int cs = c ^ (srow & 15);
      *(uint4*)(&sW[srow * 128 + cs * 8]) = *(const uint4*)(src + j * 8);
    }
  }
  __syncthreads();

  // ---- phase 1: gate for this wave's 16 rows (weights from LDS) ----
  if (act) {
    f32x4 acc[8];
#pragma unroll
    for (int ct = 0; ct < 8; ct++) {
      float b = ba[ct * 16 + lrow];
      acc[ct] = (f32x4){b, b, b, b};
    }
    int ar = r0 + lrow;
    if (ar >= nrows) ar = nrows - 1;
    const unsigned short* Ap = A + (size_t)ar * CD;
#pragma unroll
    for (int kc = 0; kc < 4; kc++) {
      bf16x8 af = *(const bf16x8*)(Ap + kc * 32 + k0);
#pragma unroll
      for (int ct = 0; ct < 8; ct++) {
        int cs = (kc * 4 + quad) ^ lrow;  // row=(ct*16+lrow), row&15==lrow
        bf16x8 bfr = *(const bf16x8*)(&sW[(ct * 16 + lrow) * 128 + cs * 8]);
        acc[ct] = __builtin_amdgcn_mfma_f32_16x16x32_bf16(af, bfr, acc[ct], 0, 0, 0);
      }
    }
    float gg = 1.f / (1.f + __expf(-skip[0]));
#pragma unroll
    for (int ct = 0; ct < 8; ct++) {
#pragma unroll
      for (int i = 0; i < 4; i++) {
        int gr = r0 + quad * 4 + i;
        if (gr >= nrows) continue;
        size_t ix = (size_t)gr * CD + ct * 16 + lrow;
        float hres = xf32 ? ((const float*)xres)[ix]
                          : bfbits2f((unsigned int)((const unsigned short*)xres)[ix]);
        float o = gg * acc[ct][i] + (1.f - gg) * hres;
        h[ix] = o;
        sA[gr - blkbase][ct * 16 + lrow] = f2bfbits(o);
      }
    }
  }
  __syncthreads();  // sA ready; Wa reads done (sW free to overwrite)

  // ---- phase 2: qkv-l1; weights staged per projection, A from sA ----
  int ar = r0 + lrow;
  if (ar >= nrows) ar = nrows - 1;
  const unsigned short* Alds = &sA[ar - blkbase][0];
#pragma unroll 1
  for (int which = 0; which < 3; which++) {
    const unsigned short* BT = (which == 0) ? wq1 : (which == 1) ? wk1 : wv1;
    const float* bias = (which == 0) ? bq1 : (which == 1) ? bk1 : bv1;
    {
      const unsigned short* src = BT + (size_t)srow * CD + shf * 64;
#pragma unroll
      for (int j = 0; j < 8; j++) {
        int c = shf * 8 + j;
        int cs = c ^ (srow & 15);
        *(uint4*)(&sW[srow * 128 + cs * 8]) = *(const uint4*)(src + j * 8);
      }
    }
    __syncthreads();  // sW staged
    if (act) {
      f32x4 acc[8];
#pragma unroll
      for (int ct = 0; ct < 8; ct++) {
        float b = bias[ct * 16 + lrow];
        acc[ct] = (f32x4){b, b, b, b};
      }
#pragma unroll
      for (int kc = 0; kc < 4; kc++) {
        bf16x8 af = *(const bf16x8*)(Alds + kc * 32 + k0);
#pragma unroll
        for (int ct = 0; ct < 8; ct++) {
          int cs = (kc * 4 + quad) ^ lrow;
          bf16x8 bfr = *(const bf16x8*)(&sW[(ct * 16 + lrow) * 128 + cs * 8]);
          acc[ct] = __builtin_amdgcn_mfma_f32_16x16x32_bf16(af, bfr, acc[ct], 0, 0, 0);
        }
      }
#pragma unroll
      for (int ct = 0; ct < 8; ct++) {
#pragma unroll
        for (int i = 0; i < 4; i++) {
          int gr = r0 + quad * 4 + i;
          if (gr >= nrows) continue;
          int col = ct * 16 + lrow;
          float val = acc[ct][i];
          if (which == 0) {
            qout[(size_t)gr * CD + col] = val;
          } else {
            unsigned short* o = kvout + ((size_t)gr << 8) + ((which == 2) ? CD : 0);
            o[col] = f2bfbits(val);
          }
        }
      }
    }
    __syncthreads();  // reads done before next stage overwrites sW
  }
}

// ==== gate MFMA GEMM, FINAL layer only (r9, unchanged). ====
__global__ __launch_bounds__(256, 4) void k_gemm_gate(
    const unsigned short* __restrict__ A, const unsigned short* __restrict__ BT,
    const float* __restrict__ bias, const float* __restrict__ h,
    const float* __restrict__ skip,
    const float* __restrict__ Wfc, const float* __restrict__ bfc,
    void* __restrict__ out, const int* __restrict__ flags, int nrows) {
  const int w = threadIdx.x >> 6;
  const int l = threadIdx.x & 63;
  const int r0 = blockIdx.x * 64 + w * 16;
  if (r0 >= nrows) return;
  const int lrow = l & 15;
  const int quad = l >> 4;
  const int k0 = quad * 8;
  const int xf32 = flags[0];

  f32x4 acc[8];
#pragma unroll
  for (int ct = 0; ct < 8; ct++) {
    float b = bias[ct * 16 + lrow];
    acc[ct] = (f32x4){b, b, b, b};
  }
  int ar = r0 + lrow;
  if (ar >= nrows) ar = nrows - 1;
  const unsigned short* Ap = A + (size_t)ar * CD;
#pragma unroll
  for (int kc = 0; kc < 4; kc++) {
    bf16x8 af = *(const bf16x8*)(Ap + kc * 32 + k0);
#pragma unroll
    for (int ct = 0; ct < 8; ct++) {
      bf16x8 bfr = *(const bf16x8*)(BT + (size_t)(ct * 16 + lrow) * CD + kc * 32 + k0);
      acc[ct] = __builtin_amdgcn_mfma_f32_16x16x32_bf16(af, bfr, acc[ct], 0, 0, 0);
    }
  }
  float gg = 1.f / (1.f + __expf(-skip[0]));
  float p0[4] = {0.f, 0.f, 0.f, 0.f};
  float p1[4] = {0.f, 0.f, 0.f, 0.f};
#pragma unroll
  for (int ct = 0; ct < 8; ct++) {
    float w0 = Wfc[(ct * 16 + lrow) * 2];
    float w1 = Wfc[(ct * 16 + lrow) * 2 + 1];
#pragma unroll
    for (int i = 0; i < 4; i++) {
      int gr = r0 + quad * 4 + i;
      if (gr >= nrows) continue;
      size_t ix = (size_t)gr * CD + ct * 16 + lrow;
      float o = gg * acc[ct][i] + (1.f - gg) * h[ix];
      p0[i] += o * w0;
      p1[i] += o * w1;
    }
  }
#pragma unroll
  for (int off = 1; off <= 8; off <<= 1) {
#pragma unroll
    for (int i = 0; i < 4; i++) {
      p0[i] += __shfl_xor(p0[i], off);
      p1[i] += __shfl_xor(p1[i], off);
    }
  }
  if (lrow == 0) {
#pragma unroll
    for (int i = 0; i < 4; i++) {
      int gr = r0 + quad * 4 + i;
      if (gr >= nrows) continue;
      float o0 = p0[i] + bfc[0];
      float o1 = p1[i] + bfc[1];
      if (xf32) {
        ((float*)out)[(size_t)gr * 2] = o0;
        ((float*)out)[(size_t)gr * 2 + 1] = o1;
      } else {
        ((bf16*)out)[(size_t)gr * 2] = __float2bfloat16(o0);
        ((bf16*)out)[(size_t)gr * 2 + 1] = __float2bfloat16(o1);
      }
    }
  }
}

// ---- per-edge compute: unpack k/v, dot with q, exp, accumulate ----
__device__ __forceinline__ void edge_acc(uint4 ku, uint4 vu, float4 qa, float4 qb,
                                         float* __restrict__ acc, float& den) {
  float k0 = bfbits2f(ku.x & 0xffffu), k1 = bfbits2f(ku.x >> 16);
  float k2 = bfbits2f(ku.y & 0xffffu), k3 = bfbits2f(ku.y >> 16);
  float k4 = bfbits2f(ku.z & 0xffffu), k5 = bfbits2f(ku.z >> 16);
  float k6 = bfbits2f(ku.w & 0xffffu), k7 = bfbits2f(ku.w >> 16);
  float v0 = bfbits2f(vu.x & 0xffffu), v1 = bfbits2f(vu.x >> 16);
  float v2 = bfbits2f(vu.y & 0xffffu), v3 = bfbits2f(vu.y >> 16);
  float v4 = bfbits2f(vu.z & 0xffffu), v5 = bfbits2f(vu.z >> 16);
  float v6 = bfbits2f(vu.w & 0xffffu), v7 = bfbits2f(vu.w >> 16);
  float pd = qa.x * k0 + qa.y * k1 + qa.z * k2 + qa.w * k3 +
             qb.x * k4 + qb.y * k5 + qb.z * k6 + qb.w * k7;
  pd += __shfl_xor(pd, 1);
  pd += __shfl_xor(pd, 2);
  float ew = __expf(fminf(pd, 60.f));  // no max-sub: |logit| ~ O(1), safe
  acc[0] += ew * v0; acc[1] += ew * v1;
  acc[2] += ew * v2; acc[3] += ew * v3;
  acc[4] += ew * v4; acc[5] += ew * v5;
  acc[6] += ew * v6; acc[7] += ew * v7;
  den += ew;
}

// ==== fused attention (unchanged; pinned at the random-256B-gather
// throughput ceiling ~3.75 TB/s across 3 schedules / occupancies 67-77%). ====
__global__ __launch_bounds__(256) void k_edge(
    const float* __restrict__ q, const unsigned short* __restrict__ kv,
    const int* __restrict__ rowptr, const int* __restrict__ deg,
    const int* __restrict__ csr_src, const float* __restrict__ p_rel,
    unsigned short* __restrict__ agg16, int N) {
  int n = (blockIdx.x * 256 + threadIdx.x) >> 6;
  if (n >= N) return;
  const int lane = threadIdx.x & 63;
  const int g = lane >> 4;
  const int j = lane & 15;
  const int start = rowptr[n];
  const int end = start + deg[n];
  const float prl = p_rel[j >> 2] * 0.17677669529663687f;  // 1/sqrt(32)
  float4 qa = *(const float4*)(q + (size_t)n * CD + 8 * j);
  float4 qb = *(const float4*)(q + (size_t)n * CD + 8 * j + 4);
  qa.x *= prl; qa.y *= prl; qa.z *= prl; qa.w *= prl;
  qb.x *= prl; qb.y *= prl; qb.z *= prl; qb.w *= prl;
  float den = 0.f;
  float acc[8] = {0.f, 0.f, 0.f, 0.f, 0.f, 0.f, 0.f, 0.f};
  int e = start + g;
  if (e < end) {
    const int last = end - 1;
    bool bok = (e + 4) < end;
    int sa = csr_src[e];
    int sb = csr_src[bok ? e + 4 : e];
    const unsigned short* pa = kv + ((size_t)sa << 8) + 8 * j;
    const unsigned short* pb = kv + ((size_t)sb << 8) + 8 * j;
    uint4 kua = *(const uint4*)pa;
    uint4 vua = *(const uint4*)(pa + CD);
    uint4 kub = *(const uint4*)pb;
    uint4 vub = *(const uint4*)(pb + CD);
    for (;;) {
      const int en = e + 8;
      int ea2 = (en < last) ? en : last;
      int eb2 = (en + 4 < last) ? en + 4 : last;
      int sa2 = csr_src[ea2];
      int sb2 = csr_src[eb2];
      const unsigned short* pa2 = kv + ((size_t)sa2 << 8) + 8 * j;
      const unsigned short* pb2 = kv + ((size_t)sb2 << 8) + 8 * j;
      uint4 kua2 = *(const uint4*)pa2;
      uint4 vua2 = *(const uint4*)(pa2 + CD);
      uint4 kub2 = *(const uint4*)pb2;
      uint4 vub2 = *(const uint4*)(pb2 + CD);
      __builtin_amdgcn_sched_barrier(0);
      edge_acc(kua, vua, qa, qb, acc, den);
      if (bok) edge_acc(kub, vub, qa, qb, acc, den);
      if (en >= end) break;
      e = en;
      bok = (en + 4) < end;
      kua = kua2; vua = vua2; kub = kub2; vub = vub2;
    }
  }
#pragma unroll
  for (int off = 16; off <= 32; off <<= 1) {
    den += __shfl_xor(den, off);
#pragma unroll
    for (int i = 0; i < 8; i++) acc[i] += __shfl_xor(acc[i], off);
  }
  if (g == 0) {
    float inv = (den > 0.f) ? 1.f / den : 0.f;
    ushort4 o0, o1;
    o0.x = f2bfbits(gelu_f(acc[0] * inv)); o0.y = f2bfbits(gelu_f(acc[1] * inv));
    o0.z = f2bfbits(gelu_f(acc[2] * inv)); o0.w = f2bfbits(gelu_f(acc[3] * inv));
    o1.x = f2bfbits(gelu_f(acc[4] * inv)); o1.y = f2bfbits(gelu_f(acc[5] * inv));
    o1.z = f2bfbits(gelu_f(acc[6] * inv)); o1.w = f2bfbits(gelu_f(acc[7] * inv));
    *(ushort4*)(agg16 + (size_t)n * CD + 8 * j) = o0;
    *(ushort4*)(agg16 + (size_t)n * CD + 8 * j + 4) = o1;
  }
}

extern "C" void kernel_launch(void* const* d_in, const int* in_sizes, int n_in,
                              void* d_out, int out_size, void* d_ws, size_t ws_size,
                              hipStream_t stream) {
  const int* ei = (const int*)d_in[1];
  const int N = in_sizes[0] / CD;
  const int E = in_sizes[1] / 2;
  const size_t NC = (size_t)N * CD;
  const int nB = (N + 255) / 256;
  int shift = 0;
  while (((N - 1) >> shift) >= 256) shift++;  // 256 coarse buckets

  float* p = (float*)d_ws;
  float* hbuf = p;                                    // NC f32 (h1 storage)
  float* qbuf = p + NC;                               // NC f32
  float* cur = p + 2 * NC;
  unsigned short* kvbuf16 = (unsigned short*)cur; cur += NC;  // N x 256 bf16 (k|v)
  unsigned short* agg16 = (unsigned short*)cur; cur += NC / 2;
  int* ip = (int*)cur;
  int* deg = ip;
  int* tmp = ip + N;
  int* rowptr = ip + 2 * N;
  int* fill = ip + 3 * N;
  int* bsum = ip + 4 * N;
  int* csr_src = ip + 4 * N + nB;
  int* bcnt = csr_src + E;     // 256
  int* bbase = bcnt + 256;     // 256
  int* bfill = bbase + 256;    // 256
  cur = (float*)(bfill + 256);
  unsigned short* wkeT = (unsigned short*)cur; cur += (size_t)LL * CD * CD / 2;
  unsigned short* wveT = (unsigned short*)cur; cur += (size_t)LL * CD * CD / 2;
  unsigned short* wqT = (unsigned short*)cur; cur += (size_t)LL * CD * CD / 2;
  unsigned short* waT = (unsigned short*)cur; cur += (size_t)LL * CD * CD / 2;
  float* bke = cur; cur += (size_t)LL * CD;
  float* bve = cur; cur += (size_t)LL * CD;
  float* pblock = cur;
  float* pWk = cur; cur += (size_t)LL * CD * CD;
  float* pbk = cur; cur += (size_t)LL * CD;
  float* pWq = cur; cur += (size_t)LL * CD * CD;
  float* pbq = cur; cur += (size_t)LL * CD;
  float* pWv = cur; cur += (size_t)LL * CD * CD;
  float* pbv = cur; cur += (size_t)LL * CD;
  float* par = cur; cur += (size_t)LL * HH * DH * DH;
  float* pmr = cur; cur += (size_t)LL * HH * DH * DH;
  float* ppr = cur; cur += (size_t)LL * HH;
  float* pWa = cur; cur += (size_t)LL * CD * CD;
  float* pba = cur; cur += (size_t)LL * CD;
  float* pskip = cur; cur += LL;
  float* pWfc = cur; cur += (size_t)CD * 2;
  float* pbfc = cur; cur += 2;
  int* flags = (int*)cur;

  // binned-edge staging aliases kvbuf16 (only used before layer loop)
  int* ebs = (int*)kvbuf16;      // E ints
  int* ebd = ebs + E;            // E ints

  SegTab tab;
  const int sizes[NSEG] = {LL * CD * CD, LL * CD, LL * CD * CD, LL * CD,
                           LL * CD * CD, LL * CD, LL * HH * DH * DH,
                           LL * HH * DH * DH, LL * HH, LL * CD * CD, LL * CD,
                           LL, CD * 2, 2};
  const int srcIdx[NSEG] = {2, 3, 4, 5, 6, 7, 8, 9, 10, 11, 12, 13, 14, 15};
  int off = 0;
  for (int k = 0; k < NSEG; k++) {
    tab.src[k] = d_in[srcIdx[k]];
    tab.off[k] = off;
    off += sizes[k];
  }
  tab.total = off;

  hipMemsetAsync(deg, 0, (size_t)N * sizeof(int), stream);
  hipMemsetAsync(bcnt, 0, 256 * sizeof(int), stream);
  k_detect<<<1, 128, 0, stream>>>(d_in[0], ei, flags);

  const int parB = (tab.total + 255) / 256;
  const int histB = (E + BTILE - 1) / BTILE;
  k_pre<<<parB + histB, 256, 0, stream>>>(tab, pblock, ei, deg, bcnt, E, N,
                                          shift, flags, parB);

  const int effB = (LL * 2 * (CD + 1) * HH * DH + 255) / 256;
  const int wtB = (LL * 2 * CD * CD) / 256;
  k_w1<<<effB + wtB + nB, 256, 0, stream>>>(
      pWk, pbk, pWv, pbv, par, pmr, wkeT, bke, wveT, bve,
      pWq, pWa, wqT, waT, deg, tmp, bsum, N, effB, wtB);

  k_s2<<<2, 256, 0, stream>>>(bsum, nB, bcnt, bbase, bfill);
  k_s3bin<<<nB + histB, 256, 0, stream>>>(tmp, deg, bsum, rowptr, fill, N, nB,
                                          ei, bfill, ebs, ebd, flags, E, N, shift);
  k_scatter2<<<512, 256, 0, stream>>>(bbase, bcnt, ebs, ebd, fill, csr_src);

  const int mfmaBlocks = (N + 63) / 64;

  // layer 0 qkv (from raw x)
  k_gemm_qkv<<<dim3(mfmaBlocks, 3), 256, 0, stream>>>(
      d_in[0], 1, flags, wqT, wkeT, wveT, pbq, bke, bve, qbuf, kvbuf16, N);

  // layer 0 edge attention
  k_edge<<<(N + 3) / 4, 256, 0, stream>>>(qbuf, kvbuf16, rowptr, deg,
                                          csr_src, ppr, agg16, N);

  // fused: gate-l0 (residual from x) + qkv-l1 (A + weights from LDS)
  k_gate_qkv<<<mfmaBlocks, 256, 0, stream>>>(
      agg16, waT, pba, d_in[0], hbuf, pskip, flags,
      wqT + (size_t)CD * CD, wkeT + (size_t)CD * CD, wveT + (size_t)CD * CD,
      pbq + CD, bke + CD, bve + CD, qbuf, kvbuf16, N);

  // layer 1 edge attention
  k_edge<<<(N + 3) / 4, 256, 0, stream>>>(qbuf, kvbuf16, rowptr, deg,
                                          csr_src, ppr + HH, agg16, N);

  // layer 1 gate + fused final projection
  k_gemm_gate<<<mfmaBlocks, 256, 0, stream>>>(
      agg16, waT + (size_t)CD * CD, pba + CD, hbuf, pskip + 1,
      pWfc, pbfc, d_out, flags, N);
}

// Round 11
// 656.840 us; speedup vs baseline: 1.1994x; 1.1007x over previous
//
#include <hip/hip_runtime.h>
#include <hip/hip_bf16.h>
#include <math.h>

#define CD 128
#define HH 4
#define DH 32
#define LL 2

using bf16 = __hip_bfloat16;
using bf16x8 = __attribute__((ext_vector_type(8))) short;  // 8 bf16 (4 VGPRs)
using f32x4 = __attribute__((ext_vector_type(4))) float;

__device__ __forceinline__ float bfbits2f(unsigned int s) {
  return __uint_as_float(s << 16);
}

__device__ __forceinline__ unsigned short f2bfbits(float f) {
  unsigned int u = __float_as_uint(f);
  unsigned int r = (u + 0x7fff + ((u >> 16) & 1)) >> 16;  // RNE
  return (unsigned short)r;
}

__device__ __forceinline__ float gelu_f(float x) {
  return 0.5f * x * (1.0f + erff(x * 0.70710678118654752f));
}

// ---- detect input formats: flags[0]=floats-are-f32, flags[1]=edge-index-is-i64 ----
__global__ void k_detect(const void* __restrict__ x, const int* __restrict__ ei,
                         int* __restrict__ flags) {
  __shared__ int cnt_f32, cnt_i32;
  if (threadIdx.x == 0) { cnt_f32 = 0; cnt_i32 = 0; }
  __syncthreads();
  int t = threadIdx.x;  // 128 threads
  unsigned short u = ((const unsigned short*)x)[2 * t];
  float v = bfbits2f((unsigned int)u);
  float av = fabsf(v);
  if (av != 0.f && (av > 1e8f || av < 1e-8f)) atomicAdd(&cnt_f32, 1);
  if (t < 64) {
    if (((const int*)ei)[2 * t + 1] != 0) atomicAdd(&cnt_i32, 1);
  }
  __syncthreads();
  if (threadIdx.x == 0) {
    flags[0] = (cnt_f32 > 8) ? 1 : 0;
    flags[1] = (cnt_i32 == 0) ? 1 : 0;
  }
}

#define NSEG 14
struct SegTab {
  const void* src[NSEG];
  int off[NSEG];
  int total;
};

__device__ __forceinline__ int edge_idx(const int* __restrict__ ei, long pos, int is64) {
  return is64 ? ei[2 * pos] : ei[pos];
}

#define BTILE 4096

// ==== FUSED pre-pass: {cvt_params, histb} (r5) ====
__global__ __launch_bounds__(256) void k_pre(
    SegTab tab, float* __restrict__ pdst,
    const int* __restrict__ ei, int* __restrict__ deg, int* __restrict__ bcnt,
    int E, int Nn, int shift, const int* __restrict__ flags, int parB) {
  __shared__ int cnt[256];
  const int bx = blockIdx.x;
  if (bx < parB) {
    int i = bx * 256 + threadIdx.x;
    if (i >= tab.total) return;
    int seg = 0;
#pragma unroll
    for (int k = 1; k < NSEG; k++)
      if (i >= tab.off[k]) seg = k;
    int j = i - tab.off[seg];
    const void* src = tab.src[seg];
    pdst[i] = flags[0] ? ((const float*)src)[j]
                       : bfbits2f((unsigned int)((const unsigned short*)src)[j]);
  } else {
    cnt[threadIdx.x] = 0;
    __syncthreads();
    const int t0 = (bx - parB) * BTILE;
    const int is64 = flags[1];
    for (int j = 0; j < 16; j++) {
      int i = t0 + threadIdx.x + j * 256;
      if (i < E) {
        int d = edge_idx(ei, (long)E + i, is64);
        if ((unsigned)d >= (unsigned)Nn) d = 0;
        atomicAdd(&deg[d], 1);
        atomicAdd(&cnt[d >> shift], 1);
      }
    }
    __syncthreads();
    int v = cnt[threadIdx.x];
    if (v > 0) atomicAdd(&bcnt[threadIdx.x], v);
  }
}

// ==== FUSED stage 2: {eff, wt, scan1} (r4, unchanged) ====
__global__ __launch_bounds__(256) void k_w1(
    const float* __restrict__ pWk, const float* __restrict__ pbk,
    const float* __restrict__ pWv, const float* __restrict__ pbv,
    const float* __restrict__ par, const float* __restrict__ pmr,
    unsigned short* __restrict__ wkeT, float* __restrict__ bke,
    unsigned short* __restrict__ wveT, float* __restrict__ bve,
    const float* __restrict__ pWq, const float* __restrict__ pWa,
    unsigned short* __restrict__ wqT, unsigned short* __restrict__ waT,
    const int* __restrict__ deg, int* __restrict__ tmp, int* __restrict__ bsum,
    int n, int effB, int wtB) {
  __shared__ int sh[256];
  const int bx = blockIdx.x;
  if (bx < effB) {
    int i = bx * 256 + threadIdx.x;
    const int total = LL * 2 * (CD + 1) * HH * DH;
    if (i >= total) return;
    int e = i & 31;
    int h = (i >> 5) & 3;
    int c = (i >> 7) % (CD + 1);
    int z = (i >> 7) / (CD + 1);
    int l = z >> 1, which = z & 1;
    const float* W = (which ? pWv : pWk) + (size_t)l * CD * CD;
    const float* B = (which ? pbv : pbk) + (size_t)l * CD;
    const float* R = (which ? pmr : par) + (size_t)l * HH * DH * DH + h * DH * DH;
    unsigned short* WoT = (which ? wveT : wkeT) + (size_t)l * CD * CD;
    float* Bo = (which ? bve : bke) + (size_t)l * CD;
    float acc = 0.f;
    if (c < CD) {
#pragma unroll
      for (int d = 0; d < DH; d++) acc += W[c * CD + h * DH + d] * R[d * DH + e];
      WoT[(size_t)(h * DH + e) * CD + c] = f2bfbits(acc);
    } else {
#pragma unroll
      for (int d = 0; d < DH; d++) acc += B[h * DH + d] * R[d * DH + e];
      Bo[h * DH + e] = acc;
    }
  } else if (bx < effB + wtB) {
    int i = (bx - effB) * 256 + threadIdx.x;  // < LL*2*CD*CD exactly
    int cin = i & 127;
    int cout = (i >> 7) & 127;
    int z = i >> 14;
    int l = z >> 1, which = z & 1;
    const float* W = (which ? pWa : pWq) + (size_t)l * CD * CD;
    unsigned short* WT = (which ? waT : wqT) + (size_t)l * CD * CD;
    WT[(size_t)cout * CD + cin] = f2bfbits(W[(size_t)cin * CD + cout]);
  } else {
    const int b = bx - effB - wtB;
    int i = b * 256 + threadIdx.x;
    int v = (i < n) ? deg[i] : 0;
    sh[threadIdx.x] = v;
    __syncthreads();
    for (int off = 1; off < 256; off <<= 1) {
      int t = (threadIdx.x >= off) ? sh[threadIdx.x - off] : 0;
      __syncthreads();
      sh[threadIdx.x] += t;
      __syncthreads();
    }
    if (i < n) tmp[i] = sh[threadIdx.x];
    if (threadIdx.x == 255) bsum[b] = sh[255];
  }
}

// ==== FUSED stage 3: {scan2, bscan} (r4, unchanged) ====
__global__ __launch_bounds__(256) void k_s2(
    int* __restrict__ bsum, int nb, const int* __restrict__ bcnt,
    int* __restrict__ bbase, int* __restrict__ bfill) {
  __shared__ int sh[256];
  __shared__ int carry;
  if (blockIdx.x == 0) {
    if (threadIdx.x == 0) carry = 0;
    __syncthreads();
    for (int base = 0; base < nb; base += 256) {
      int i = base + threadIdx.x;
      int v = (i < nb) ? bsum[i] : 0;
      sh[threadIdx.x] = v;
      __syncthreads();
      for (int off = 1; off < 256; off <<= 1) {
        int t = (threadIdx.x >= off) ? sh[threadIdx.x - off] : 0;
        __syncthreads();
        sh[threadIdx.x] += t;
        __syncthreads();
      }
      if (i < nb) bsum[i] = sh[threadIdx.x] + carry;
      __syncthreads();
      if (threadIdx.x == 0) carry += sh[255];
      __syncthreads();
    }
  } else {
    int t = threadIdx.x;
    int v = bcnt[t];
    sh[t] = v;
    __syncthreads();
    for (int off = 1; off < 256; off <<= 1) {
      int u = (t >= off) ? sh[t - off] : 0;
      __syncthreads();
      sh[t] += u;
      __syncthreads();
    }
    int excl = sh[t] - v;
    bbase[t] = excl;
    bfill[t] = excl;
  }
}

// ==== FUSED stage 4: {scan3, bin} (r4, unchanged) ====
__global__ __launch_bounds__(256) void k_s3bin(
    const int* __restrict__ tmp, const int* __restrict__ deg,
    const int* __restrict__ bsum, int* __restrict__ rowptr,
    int* __restrict__ fill, int n, int nB,
    const int* __restrict__ ei, int* __restrict__ bfill,
    int* __restrict__ ebs, int* __restrict__ ebd,
    const int* __restrict__ flags, int E, int Nn, int shift) {
  __shared__ int sS[BTILE];
  __shared__ int sD[BTILE];
  __shared__ int cnt[256], pref[256], base[256], lofs[256];
  const int bx = blockIdx.x;
  if (bx < nB) {
    int i = bx * 256 + threadIdx.x;
    if (i >= n) return;
    int off = (bx > 0) ? bsum[bx - 1] : 0;
    int excl = tmp[i] - deg[i] + off;
    rowptr[i] = excl;
    fill[i] = excl;
    return;
  }
  const int t = threadIdx.x;
  cnt[t] = 0;
  lofs[t] = 0;
  __syncthreads();
  const int t0 = (bx - nB) * BTILE;
  const int is64 = flags[1];
  for (int j = 0; j < 16; j++) {
    int i = t0 + t + j * 256;
    if (i < E) {
      int d = edge_idx(ei, (long)E + i, is64);
      if ((unsigned)d >= (unsigned)Nn) d = 0;
      atomicAdd(&cnt[d >> shift], 1);
    }
  }
  __syncthreads();
  {
    int v = cnt[t];
    pref[t] = v;
    __syncthreads();
    for (int off = 1; off < 256; off <<= 1) {
      int u = (t >= off) ? pref[t - off] : 0;
      __syncthreads();
      pref[t] += u;
      __syncthreads();
    }
    int incl = pref[t];
    __syncthreads();
    pref[t] = incl - v;
    base[t] = (v > 0) ? atomicAdd(&bfill[t], v) : 0;
  }
  __syncthreads();
  for (int j = 0; j < 16; j++) {
    int i = t0 + t + j * 256;
    if (i < E) {
      int s = edge_idx(ei, (long)i, is64);
      int d = edge_idx(ei, (long)E + i, is64);
      if ((unsigned)s >= (unsigned)Nn) s = 0;
      if ((unsigned)d >= (unsigned)Nn) d = 0;
      int b = d >> shift;
      int p = pref[b] + atomicAdd(&lofs[b], 1);
      sS[p] = s;
      sD[p] = d;
    }
  }
  __syncthreads();
  int tot = E - t0;
  if (tot > BTILE) tot = BTILE;
  for (int j = 0; j < 16; j++) {
    int i = t + j * 256;
    if (i < tot) {
      int d = sD[i];
      int b = d >> shift;
      int gp = base[b] + (i - pref[b]);
      ebs[gp] = sS[i];
      ebd[gp] = d;
    }
  }
}

// final scatter within per-bucket csr window (L2-local)
__global__ void k_scatter2(const int* __restrict__ bbase, const int* __restrict__ bcnt,
                           const int* __restrict__ ebs, const int* __restrict__ ebd,
                           int* __restrict__ fill, int* __restrict__ csr_src) {
  int b = blockIdx.x >> 1, half = blockIdx.x & 1;
  int s0 = bbase[b], c = bcnt[b];
  int st = s0 + (half ? (c + 1) / 2 : 0);
  int en = s0 + (half ? c : (c + 1) / 2);
  for (int i = st + threadIdx.x; i < en; i += 256) {
    int s = ebs[i], d = ebd[i];
    int pos = atomicAdd(&fill[d], 1);
    csr_src[pos] = s;
  }
}

// ==== qkv layer 0 (r11 rewrite): single grid, A (raw x) loaded ONCE into
// 16 VGPRs, then 3 SEQUENTIAL projections (unroll 1 — one 32-reg acc at a
// time, r7/r8 lesson) each with the r10-proven XOR-swizzled LDS weight stage.
// Kills: 2x re-read of x (77->26 MB) + per-wave L2 weight streaming (the
// r9 latency pathology) + 2/3 of the blocks. Math bit-identical. ====
__global__ __launch_bounds__(256, 4) void k_gemm_qkv(
    const void* __restrict__ Araw, const int* __restrict__ flags,
    const unsigned short* __restrict__ wq, const unsigned short* __restrict__ wk,
    const unsigned short* __restrict__ wv,
    const float* __restrict__ bq, const float* __restrict__ bk,
    const float* __restrict__ bv,
    float* __restrict__ qout, unsigned short* __restrict__ kvout, int nrows) {
  __shared__ unsigned short sW[128 * 128];
  const int t = threadIdx.x;
  const int w = t >> 6;
  const int l = t & 63;
  const int r0 = blockIdx.x * 64 + w * 16;
  const int lrow = l & 15;
  const int quad = l >> 4;
  const int k0 = quad * 8;
  const bool act = (r0 < nrows);
  const int srow = t >> 1;
  const int shf = t & 1;
  const int ax_f32 = flags[0];

  // ---- load A fragments once (kept live across all 3 projections) ----
  bf16x8 afr[4];
  if (act) {
    int ar = r0 + lrow;
    if (ar >= nrows) ar = nrows - 1;
#pragma unroll
    for (int kc = 0; kc < 4; kc++) {
      if (ax_f32) {
        const float* Af = (const float*)Araw + (size_t)ar * CD + kc * 32 + k0;
        float4 a = *(const float4*)Af;
        float4 b = *(const float4*)(Af + 4);
        afr[kc][0] = (short)f2bfbits(a.x); afr[kc][1] = (short)f2bfbits(a.y);
        afr[kc][2] = (short)f2bfbits(a.z); afr[kc][3] = (short)f2bfbits(a.w);
        afr[kc][4] = (short)f2bfbits(b.x); afr[kc][5] = (short)f2bfbits(b.y);
        afr[kc][6] = (short)f2bfbits(b.z); afr[kc][7] = (short)f2bfbits(b.w);
      } else {
        afr[kc] = *(const bf16x8*)((const unsigned short*)Araw +
                                   (size_t)ar * CD + kc * 32 + k0);
      }
    }
  }

#pragma unroll 1
  for (int which = 0; which < 3; which++) {
    const unsigned short* BT = (which == 0) ? wq : (which == 1) ? wk : wv;
    const float* bias = (which == 0) ? bq : (which == 1) ? bk : bv;
    // stage weights (all 256 threads; barrier outside act guard)
    {
      const unsigned short* src = BT + (size_t)srow * CD + shf * 64;
#pragma unroll
      for (int j = 0; j < 8; j++) {
        int c = shf * 8 + j;
        int cs = c ^ (srow & 15);
        *(uint4*)(&sW[srow * 128 + cs * 8]) = *(const uint4*)(src + j * 8);
      }
    }
    __syncthreads();
    if (act) {
      f32x4 acc[8];
#pragma unroll
      for (int ct = 0; ct < 8; ct++) {
        float b = bias[ct * 16 + lrow];
        acc[ct] = (f32x4){b, b, b, b};
      }
#pragma unroll
      for (int kc = 0; kc < 4; kc++) {
#pragma unroll
        for (int ct = 0; ct < 8; ct++) {
          int cs = (kc * 4 + quad) ^ lrow;
          bf16x8 bfr = *(const bf16x8*)(&sW[(ct * 16 + lrow) * 128 + cs * 8]);
          acc[ct] = __builtin_amdgcn_mfma_f32_16x16x32_bf16(afr[kc], bfr, acc[ct], 0, 0, 0);
        }
      }
#pragma unroll
      for (int ct = 0; ct < 8; ct++) {
#pragma unroll
        for (int i = 0; i < 4; i++) {
          int gr = r0 + quad * 4 + i;
          if (gr >= nrows) continue;
          int col = ct * 16 + lrow;
          float val = acc[ct][i];
          if (which == 0) {
            qout[(size_t)gr * CD + col] = val;
          } else {
            unsigned short* o = kvout + ((size_t)gr << 8) + ((which == 2) ? CD : 0);
            o[col] = f2bfbits(val);
          }
        }
      }
    }
    __syncthreads();  // reads done before next stage overwrites sW
  }
}

// ==== FUSED gate-l0 + qkv-l1 (r10, unchanged — LDS weight staging). ====
__global__ __launch_bounds__(256, 3) void k_gate_qkv(
    const unsigned short* __restrict__ A, const unsigned short* __restrict__ BTa,
    const float* __restrict__ ba, const void* __restrict__ xres,
    float* __restrict__ h, const float* __restrict__ skip,
    const int* __restrict__ flags,
    const unsigned short* __restrict__ wq1, const unsigned short* __restrict__ wk1,
    const unsigned short* __restrict__ wv1,
    const float* __restrict__ bq1, const float* __restrict__ bk1,
    const float* __restrict__ bv1,
    float* __restrict__ qout, unsigned short* __restrict__ kvout, int nrows) {
  __shared__ unsigned short sA[64][136];
  __shared__ unsigned short sW[128 * 128];  // XOR-swizzled 16B chunks
  const int t = threadIdx.x;
  const int w = t >> 6;
  const int l = t & 63;
  const int blkbase = blockIdx.x * 64;
  const int r0 = blkbase + w * 16;
  const int lrow = l & 15;
  const int quad = l >> 4;
  const int k0 = quad * 8;
  const int xf32 = flags[0];
  const bool act = (r0 < nrows);
  const int srow = t >> 1;       // staging: thread pair per weight row
  const int shf = t & 1;         // which 64-col half

  // ---- stage Wa into sW (swizzled) ----
  {
    const unsigned short* src = BTa + (size_t)srow * CD + shf * 64;
#pragma unroll
    for (int j = 0; j < 8; j++) {
      int c = shf * 8 + j;
      int cs = c ^ (srow & 15);
      *(uint4*)(&sW[srow * 128 + cs * 8]) = *(const uint4*)(src + j * 8);
    }
  }
  __syncthreads();

  // ---- phase 1: gate for this wave's 16 rows (weights from LDS) ----
  if (act) {
    f32x4 acc[8];
#pragma unroll
    for (int ct = 0; ct < 8; ct++) {
      float b = ba[ct * 16 + lrow];
      acc[ct] = (f32x4){b, b, b, b};
    }
    int ar = r0 + lrow;
    if (ar >= nrows) ar = nrows - 1;
    const unsigned short* Ap = A + (size_t)ar * CD;
#pragma unroll
    for (int kc = 0; kc < 4; kc++) {
      bf16x8 af = *(const bf16x8*)(Ap + kc * 32 + k0);
#pragma unroll
      for (int ct = 0; ct < 8; ct++) {
        int cs = (kc * 4 + quad) ^ lrow;  // row=(ct*16+lrow), row&15==lrow
        bf16x8 bfr = *(const bf16x8*)(&sW[(ct * 16 + lrow) * 128 + cs * 8]);
        acc[ct] = __builtin_amdgcn_mfma_f32_16x16x32_bf16(af, bfr, acc[ct], 0, 0, 0);
      }
    }
    float gg = 1.f / (1.f + __expf(-skip[0]));
#pragma unroll
    for (int ct = 0; ct < 8; ct++) {
#pragma unroll
      for (int i = 0; i < 4; i++) {
        int gr = r0 + quad * 4 + i;
        if (gr >= nrows) continue;
        size_t ix = (size_t)gr * CD + ct * 16 + lrow;
        float hres = xf32 ? ((const float*)xres)[ix]
                          : bfbits2f((unsigned int)((const unsigned short*)xres)[ix]);
        float o = gg * acc[ct][i] + (1.f - gg) * hres;
        h[ix] = o;
        sA[gr - blkbase][ct * 16 + lrow] = f2bfbits(o);
      }
    }
  }
  __syncthreads();  // sA ready; Wa reads done (sW free to overwrite)

  // ---- phase 2: qkv-l1; weights staged per projection, A from sA ----
  int ar = r0 + lrow;
  if (ar >= nrows) ar = nrows - 1;
  const unsigned short* Alds = &sA[ar - blkbase][0];
#pragma unroll 1
  for (int which = 0; which < 3; which++) {
    const unsigned short* BT = (which == 0) ? wq1 : (which == 1) ? wk1 : wv1;
    const float* bias = (which == 0) ? bq1 : (which == 1) ? bk1 : bv1;
    {
      const unsigned short* src = BT + (size_t)srow * CD + shf * 64;
#pragma unroll
      for (int j = 0; j < 8; j++) {
        int c = shf * 8 + j;
        int cs = c ^ (srow & 15);
        *(uint4*)(&sW[srow * 128 + cs * 8]) = *(const uint4*)(src + j * 8);
      }
    }
    __syncthreads();  // sW staged
    if (act) {
      f32x4 acc[8];
#pragma unroll
      for (int ct = 0; ct < 8; ct++) {
        float b = bias[ct * 16 + lrow];
        acc[ct] = (f32x4){b, b, b, b};
      }
#pragma unroll
      for (int kc = 0; kc < 4; kc++) {
        bf16x8 af = *(const bf16x8*)(Alds + kc * 32 + k0);
#pragma unroll
        for (int ct = 0; ct < 8; ct++) {
          int cs = (kc * 4 + quad) ^ lrow;
          bf16x8 bfr = *(const bf16x8*)(&sW[(ct * 16 + lrow) * 128 + cs * 8]);
          acc[ct] = __builtin_amdgcn_mfma_f32_16x16x32_bf16(af, bfr, acc[ct], 0, 0, 0);
        }
      }
#pragma unroll
      for (int ct = 0; ct < 8; ct++) {
#pragma unroll
        for (int i = 0; i < 4; i++) {
          int gr = r0 + quad * 4 + i;
          if (gr >= nrows) continue;
          int col = ct * 16 + lrow;
          float val = acc[ct][i];
          if (which == 0) {
            qout[(size_t)gr * CD + col] = val;
          } else {
            unsigned short* o = kvout + ((size_t)gr << 8) + ((which == 2) ? CD : 0);
            o[col] = f2bfbits(val);
          }
        }
      }
    }
    __syncthreads();  // reads done before next stage overwrites sW
  }
}

// ==== gate MFMA GEMM, FINAL layer only (r11: + LDS weight staging). ====
__global__ __launch_bounds__(256, 4) void k_gemm_gate(
    const unsigned short* __restrict__ A, const unsigned short* __restrict__ BT,
    const float* __restrict__ bias, const float* __restrict__ h,
    const float* __restrict__ skip,
    const float* __restrict__ Wfc, const float* __restrict__ bfc,
    void* __restrict__ out, const int* __restrict__ flags, int nrows) {
  __shared__ unsigned short sW[128 * 128];
  const int t = threadIdx.x;
  const int w = t >> 6;
  const int l = t & 63;
  const int r0 = blockIdx.x * 64 + w * 16;
  const int lrow = l & 15;
  const int quad = l >> 4;
  const int k0 = quad * 8;
  const int xf32 = flags[0];
  const bool act = (r0 < nrows);
  const int srow = t >> 1;
  const int shf = t & 1;

  {
    const unsigned short* src = BT + (size_t)srow * CD + shf * 64;
#pragma unroll
    for (int j = 0; j < 8; j++) {
      int c = shf * 8 + j;
      int cs = c ^ (srow & 15);
      *(uint4*)(&sW[srow * 128 + cs * 8]) = *(const uint4*)(src + j * 8);
    }
  }
  __syncthreads();
  if (!act) return;

  f32x4 acc[8];
#pragma unroll
  for (int ct = 0; ct < 8; ct++) {
    float b = bias[ct * 16 + lrow];
    acc[ct] = (f32x4){b, b, b, b};
  }
  int ar = r0 + lrow;
  if (ar >= nrows) ar = nrows - 1;
  const unsigned short* Ap = A + (size_t)ar * CD;
#pragma unroll
  for (int kc = 0; kc < 4; kc++) {
    bf16x8 af = *(const bf16x8*)(Ap + kc * 32 + k0);
#pragma unroll
    for (int ct = 0; ct < 8; ct++) {
      int cs = (kc * 4 + quad) ^ lrow;
      bf16x8 bfr = *(const bf16x8*)(&sW[(ct * 16 + lrow) * 128 + cs * 8]);
      acc[ct] = __builtin_amdgcn_mfma_f32_16x16x32_bf16(af, bfr, acc[ct], 0, 0, 0);
    }
  }
  float gg = 1.f / (1.f + __expf(-skip[0]));
  float p0[4] = {0.f, 0.f, 0.f, 0.f};
  float p1[4] = {0.f, 0.f, 0.f, 0.f};
#pragma unroll
  for (int ct = 0; ct < 8; ct++) {
    float w0 = Wfc[(ct * 16 + lrow) * 2];
    float w1 = Wfc[(ct * 16 + lrow) * 2 + 1];
#pragma unroll
    for (int i = 0; i < 4; i++) {
      int gr = r0 + quad * 4 + i;
      if (gr >= nrows) continue;
      size_t ix = (size_t)gr * CD + ct * 16 + lrow;
      float o = gg * acc[ct][i] + (1.f - gg) * h[ix];
      p0[i] += o * w0;
      p1[i] += o * w1;
    }
  }
#pragma unroll
  for (int off = 1; off <= 8; off <<= 1) {
#pragma unroll
    for (int i = 0; i < 4; i++) {
      p0[i] += __shfl_xor(p0[i], off);
      p1[i] += __shfl_xor(p1[i], off);
    }
  }
  if (lrow == 0) {
#pragma unroll
    for (int i = 0; i < 4; i++) {
      int gr = r0 + quad * 4 + i;
      if (gr >= nrows) continue;
      float o0 = p0[i] + bfc[0];
      float o1 = p1[i] + bfc[1];
      if (xf32) {
        ((float*)out)[(size_t)gr * 2] = o0;
        ((float*)out)[(size_t)gr * 2 + 1] = o1;
      } else {
        ((bf16*)out)[(size_t)gr * 2] = __float2bfloat16(o0);
        ((bf16*)out)[(size_t)gr * 2 + 1] = __float2bfloat16(o1);
      }
    }
  }
}

// ---- per-edge compute: unpack k/v, dot with q, exp, accumulate ----
__device__ __forceinline__ void edge_acc(uint4 ku, uint4 vu, float4 qa, float4 qb,
                                         float* __restrict__ acc, float& den) {
  float k0 = bfbits2f(ku.x & 0xffffu), k1 = bfbits2f(ku.x >> 16);
  float k2 = bfbits2f(ku.y & 0xffffu), k3 = bfbits2f(ku.y >> 16);
  float k4 = bfbits2f(ku.z & 0xffffu), k5 = bfbits2f(ku.z >> 16);
  float k6 = bfbits2f(ku.w & 0xffffu), k7 = bfbits2f(ku.w >> 16);
  float v0 = bfbits2f(vu.x & 0xffffu), v1 = bfbits2f(vu.x >> 16);
  float v2 = bfbits2f(vu.y & 0xffffu), v3 = bfbits2f(vu.y >> 16);
  float v4 = bfbits2f(vu.z & 0xffffu), v5 = bfbits2f(vu.z >> 16);
  float v6 = bfbits2f(vu.w & 0xffffu), v7 = bfbits2f(vu.w >> 16);
  float pd = qa.x * k0 + qa.y * k1 + qa.z * k2 + qa.w * k3 +
             qb.x * k4 + qb.y * k5 + qb.z * k6 + qb.w * k7;
  pd += __shfl_xor(pd, 1);
  pd += __shfl_xor(pd, 2);
  float ew = __expf(fminf(pd, 60.f));  // no max-sub: |logit| ~ O(1), safe
  acc[0] += ew * v0; acc[1] += ew * v1;
  acc[2] += ew * v2; acc[3] += ew * v3;
  acc[4] += ew * v4; acc[5] += ew * v5;
  acc[6] += ew * v6; acc[7] += ew * v7;
  den += ew;
}

// ==== fused attention (unchanged; pinned at the random-256B-gather
// throughput ceiling ~3.75 TB/s across 3 schedules / occupancies 67-77%). ====
__global__ __launch_bounds__(256) void k_edge(
    const float* __restrict__ q, const unsigned short* __restrict__ kv,
    const int* __restrict__ rowptr, const int* __restrict__ deg,
    const int* __restrict__ csr_src, const float* __restrict__ p_rel,
    unsigned short* __restrict__ agg16, int N) {
  int n = (blockIdx.x * 256 + threadIdx.x) >> 6;
  if (n >= N) return;
  const int lane = threadIdx.x & 63;
  const int g = lane >> 4;
  const int j = lane & 15;
  const int start = rowptr[n];
  const int end = start + deg[n];
  const float prl = p_rel[j >> 2] * 0.17677669529663687f;  // 1/sqrt(32)
  float4 qa = *(const float4*)(q + (size_t)n * CD + 8 * j);
  float4 qb = *(const float4*)(q + (size_t)n * CD + 8 * j + 4);
  qa.x *= prl; qa.y *= prl; qa.z *= prl; qa.w *= prl;
  qb.x *= prl; qb.y *= prl; qb.z *= prl; qb.w *= prl;
  float den = 0.f;
  float acc[8] = {0.f, 0.f, 0.f, 0.f, 0.f, 0.f, 0.f, 0.f};
  int e = start + g;
  if (e < end) {
    const int last = end - 1;
    bool bok = (e + 4) < end;
    int sa = csr_src[e];
    int sb = csr_src[bok ? e + 4 : e];
    const unsigned short* pa = kv + ((size_t)sa << 8) + 8 * j;
    const unsigned short* pb = kv + ((size_t)sb << 8) + 8 * j;
    uint4 kua = *(const uint4*)pa;
    uint4 vua = *(const uint4*)(pa + CD);
    uint4 kub = *(const uint4*)pb;
    uint4 vub = *(const uint4*)(pb + CD);
    for (;;) {
      const int en = e + 8;
      int ea2 = (en < last) ? en : last;
      int eb2 = (en + 4 < last) ? en + 4 : last;
      int sa2 = csr_src[ea2];
      int sb2 = csr_src[eb2];
      const unsigned short* pa2 = kv + ((size_t)sa2 << 8) + 8 * j;
      const unsigned short* pb2 = kv + ((size_t)sb2 << 8) + 8 * j;
      uint4 kua2 = *(const uint4*)pa2;
      uint4 vua2 = *(const uint4*)(pa2 + CD);
      uint4 kub2 = *(const uint4*)pb2;
      uint4 vub2 = *(const uint4*)(pb2 + CD);
      __builtin_amdgcn_sched_barrier(0);
      edge_acc(kua, vua, qa, qb, acc, den);
      if (bok) edge_acc(kub, vub, qa, qb, acc, den);
      if (en >= end) break;
      e = en;
      bok = (en + 4) < end;
      kua = kua2; vua = vua2; kub = kub2; vub = vub2;
    }
  }
#pragma unroll
  for (int off = 16; off <= 32; off <<= 1) {
    den += __shfl_xor(den, off);
#pragma unroll
    for (int i = 0; i < 8; i++) acc[i] += __shfl_xor(acc[i], off);
  }
  if (g == 0) {
    float inv = (den > 0.f) ? 1.f / den : 0.f;
    ushort4 o0, o1;
    o0.x = f2bfbits(gelu_f(acc[0] * inv)); o0.y = f2bfbits(gelu_f(acc[1] * inv));
    o0.z = f2bfbits(gelu_f(acc[2] * inv)); o0.w = f2bfbits(gelu_f(acc[3] * inv));
    o1.x = f2bfbits(gelu_f(acc[4] * inv)); o1.y = f2bfbits(gelu_f(acc[5] * inv));
    o1.z = f2bfbits(gelu_f(acc[6] * inv)); o1.w = f2bfbits(gelu_f(acc[7] * inv));
    *(ushort4*)(agg16 + (size_t)n * CD + 8 * j) = o0;
    *(ushort4*)(agg16 + (size_t)n * CD + 8 * j + 4) = o1;
  }
}

extern "C" void kernel_launch(void* const* d_in, const int* in_sizes, int n_in,
                              void* d_out, int out_size, void* d_ws, size_t ws_size,
                              hipStream_t stream) {
  const int* ei = (const int*)d_in[1];
  const int N = in_sizes[0] / CD;
  const int E = in_sizes[1] / 2;
  const size_t NC = (size_t)N * CD;
  const int nB = (N + 255) / 256;
  int shift = 0;
  while (((N - 1) >> shift) >= 256) shift++;  // 256 coarse buckets

  float* p = (float*)d_ws;
  float* hbuf = p;                                    // NC f32 (h1 storage)
  float* qbuf = p + NC;                               // NC f32
  float* cur = p + 2 * NC;
  unsigned short* kvbuf16 = (unsigned short*)cur; cur += NC;  // N x 256 bf16 (k|v)
  unsigned short* agg16 = (unsigned short*)cur; cur += NC / 2;
  int* ip = (int*)cur;
  int* deg = ip;
  int* tmp = ip + N;
  int* rowptr = ip + 2 * N;
  int* fill = ip + 3 * N;
  int* bsum = ip + 4 * N;
  int* csr_src = ip + 4 * N + nB;
  int* bcnt = csr_src + E;     // 256
  int* bbase = bcnt + 256;     // 256
  int* bfill = bbase + 256;    // 256
  cur = (float*)(bfill + 256);
  unsigned short* wkeT = (unsigned short*)cur; cur += (size_t)LL * CD * CD / 2;
  unsigned short* wveT = (unsigned short*)cur; cur += (size_t)LL * CD * CD / 2;
  unsigned short* wqT = (unsigned short*)cur; cur += (size_t)LL * CD * CD / 2;
  unsigned short* waT = (unsigned short*)cur; cur += (size_t)LL * CD * CD / 2;
  float* bke = cur; cur += (size_t)LL * CD;
  float* bve = cur; cur += (size_t)LL * CD;
  float* pblock = cur;
  float* pWk = cur; cur += (size_t)LL * CD * CD;
  float* pbk = cur; cur += (size_t)LL * CD;
  float* pWq = cur; cur += (size_t)LL * CD * CD;
  float* pbq = cur; cur += (size_t)LL * CD;
  float* pWv = cur; cur += (size_t)LL * CD * CD;
  float* pbv = cur; cur += (size_t)LL * CD;
  float* par = cur; cur += (size_t)LL * HH * DH * DH;
  float* pmr = cur; cur += (size_t)LL * HH * DH * DH;
  float* ppr = cur; cur += (size_t)LL * HH;
  float* pWa = cur; cur += (size_t)LL * CD * CD;
  float* pba = cur; cur += (size_t)LL * CD;
  float* pskip = cur; cur += LL;
  float* pWfc = cur; cur += (size_t)CD * 2;
  float* pbfc = cur; cur += 2;
  int* flags = (int*)cur;

  // binned-edge staging aliases kvbuf16 (only used before layer loop)
  int* ebs = (int*)kvbuf16;      // E ints
  int* ebd = ebs + E;            // E ints

  SegTab tab;
  const int sizes[NSEG] = {LL * CD * CD, LL * CD, LL * CD * CD, LL * CD,
                           LL * CD * CD, LL * CD, LL * HH * DH * DH,
                           LL * HH * DH * DH, LL * HH, LL * CD * CD, LL * CD,
                           LL, CD * 2, 2};
  const int srcIdx[NSEG] = {2, 3, 4, 5, 6, 7, 8, 9, 10, 11, 12, 13, 14, 15};
  int off = 0;
  for (int k = 0; k < NSEG; k++) {
    tab.src[k] = d_in[srcIdx[k]];
    tab.off[k] = off;
    off += sizes[k];
  }
  tab.total = off;

  hipMemsetAsync(deg, 0, (size_t)N * sizeof(int), stream);
  hipMemsetAsync(bcnt, 0, 256 * sizeof(int), stream);
  k_detect<<<1, 128, 0, stream>>>(d_in[0], ei, flags);

  const int parB = (tab.total + 255) / 256;
  const int histB = (E + BTILE - 1) / BTILE;
  k_pre<<<parB + histB, 256, 0, stream>>>(tab, pblock, ei, deg, bcnt, E, N,
                                          shift, flags, parB);

  const int effB = (LL * 2 * (CD + 1) * HH * DH + 255) / 256;
  const int wtB = (LL * 2 * CD * CD) / 256;
  k_w1<<<effB + wtB + nB, 256, 0, stream>>>(
      pWk, pbk, pWv, pbv, par, pmr, wkeT, bke, wveT, bve,
      pWq, pWa, wqT, waT, deg, tmp, bsum, N, effB, wtB);

  k_s2<<<2, 256, 0, stream>>>(bsum, nB, bcnt, bbase, bfill);
  k_s3bin<<<nB + histB, 256, 0, stream>>>(tmp, deg, bsum, rowptr, fill, N, nB,
                                          ei, bfill, ebs, ebd, flags, E, N, shift);
  k_scatter2<<<512, 256, 0, stream>>>(bbase, bcnt, ebs, ebd, fill, csr_src);

  const int mfmaBlocks = (N + 63) / 64;

  // layer 0 qkv (from raw x; single grid, LDS-staged weights)
  k_gemm_qkv<<<mfmaBlocks, 256, 0, stream>>>(
      d_in[0], flags, wqT, wkeT, wveT, pbq, bke, bve, qbuf, kvbuf16, N);

  // layer 0 edge attention
  k_edge<<<(N + 3) / 4, 256, 0, stream>>>(qbuf, kvbuf16, rowptr, deg,
                                          csr_src, ppr, agg16, N);

  // fused: gate-l0 (residual from x) + qkv-l1 (A + weights from LDS)
  k_gate_qkv<<<mfmaBlocks, 256, 0, stream>>>(
      agg16, waT, pba, d_in[0], hbuf, pskip, flags,
      wqT + (size_t)CD * CD, wkeT + (size_t)CD * CD, wveT + (size_t)CD * CD,
      pbq + CD, bke + CD, bve + CD, qbuf, kvbuf16, N);

  // layer 1 edge attention
  k_edge<<<(N + 3) / 4, 256, 0, stream>>>(qbuf, kvbuf16, rowptr, deg,
                                          csr_src, ppr + HH, agg16, N);

  // layer 1 gate + fused final projection (LDS-staged weights)
  k_gemm_gate<<<mfmaBlocks, 256, 0, stream>>>(
      agg16, waT + (size_t)CD * CD, pba + CD, hbuf, pskip + 1,
      pWfc, pbfc, d_out, flags, N);
}

// Round 12
// 631.352 us; speedup vs baseline: 1.2479x; 1.0404x over previous
//
#include <hip/hip_runtime.h>
#include <hip/hip_bf16.h>
#include <math.h>

#define CD 128
#define HH 4
#define DH 32
#define LL 2

using bf16 = __hip_bfloat16;
using bf16x8 = __attribute__((ext_vector_type(8))) short;  // 8 bf16 (4 VGPRs)
using f32x4 = __attribute__((ext_vector_type(4))) float;

__device__ __forceinline__ float bfbits2f(unsigned int s) {
  return __uint_as_float(s << 16);
}

__device__ __forceinline__ unsigned short f2bfbits(float f) {
  unsigned int u = __float_as_uint(f);
  unsigned int r = (u + 0x7fff + ((u >> 16) & 1)) >> 16;  // RNE
  return (unsigned short)r;
}

__device__ __forceinline__ float gelu_f(float x) {
  return 0.5f * x * (1.0f + erff(x * 0.70710678118654752f));
}

// ---- detect input formats: flags[0]=floats-are-f32, flags[1]=edge-index-is-i64 ----
__global__ void k_detect(const void* __restrict__ x, const int* __restrict__ ei,
                         int* __restrict__ flags) {
  __shared__ int cnt_f32, cnt_i32;
  if (threadIdx.x == 0) { cnt_f32 = 0; cnt_i32 = 0; }
  __syncthreads();
  int t = threadIdx.x;  // 128 threads
  unsigned short u = ((const unsigned short*)x)[2 * t];
  float v = bfbits2f((unsigned int)u);
  float av = fabsf(v);
  if (av != 0.f && (av > 1e8f || av < 1e-8f)) atomicAdd(&cnt_f32, 1);
  if (t < 64) {
    if (((const int*)ei)[2 * t + 1] != 0) atomicAdd(&cnt_i32, 1);
  }
  __syncthreads();
  if (threadIdx.x == 0) {
    flags[0] = (cnt_f32 > 8) ? 1 : 0;
    flags[1] = (cnt_i32 == 0) ? 1 : 0;
  }
}

#define NSEG 14
struct SegTab {
  const void* src[NSEG];
  int off[NSEG];
  int total;
};

__device__ __forceinline__ int edge_idx(const int* __restrict__ ei, long pos, int is64) {
  return is64 ? ei[2 * pos] : ei[pos];
}

#define BTILE 4096

// ==== FUSED pre-pass: {cvt_params, histb} (r5) ====
__global__ __launch_bounds__(256) void k_pre(
    SegTab tab, float* __restrict__ pdst,
    const int* __restrict__ ei, int* __restrict__ deg, int* __restrict__ bcnt,
    int E, int Nn, int shift, const int* __restrict__ flags, int parB) {
  __shared__ int cnt[256];
  const int bx = blockIdx.x;
  if (bx < parB) {
    int i = bx * 256 + threadIdx.x;
    if (i >= tab.total) return;
    int seg = 0;
#pragma unroll
    for (int k = 1; k < NSEG; k++)
      if (i >= tab.off[k]) seg = k;
    int j = i - tab.off[seg];
    const void* src = tab.src[seg];
    pdst[i] = flags[0] ? ((const float*)src)[j]
                       : bfbits2f((unsigned int)((const unsigned short*)src)[j]);
  } else {
    cnt[threadIdx.x] = 0;
    __syncthreads();
    const int t0 = (bx - parB) * BTILE;
    const int is64 = flags[1];
    for (int j = 0; j < 16; j++) {
      int i = t0 + threadIdx.x + j * 256;
      if (i < E) {
        int d = edge_idx(ei, (long)E + i, is64);
        if ((unsigned)d >= (unsigned)Nn) d = 0;
        atomicAdd(&deg[d], 1);
        atomicAdd(&cnt[d >> shift], 1);
      }
    }
    __syncthreads();
    int v = cnt[threadIdx.x];
    if (v > 0) atomicAdd(&bcnt[threadIdx.x], v);
  }
}

// ==== FUSED stage 2: {eff, wt, scan1} (r4, unchanged) ====
__global__ __launch_bounds__(256) void k_w1(
    const float* __restrict__ pWk, const float* __restrict__ pbk,
    const float* __restrict__ pWv, const float* __restrict__ pbv,
    const float* __restrict__ par, const float* __restrict__ pmr,
    unsigned short* __restrict__ wkeT, float* __restrict__ bke,
    unsigned short* __restrict__ wveT, float* __restrict__ bve,
    const float* __restrict__ pWq, const float* __restrict__ pWa,
    unsigned short* __restrict__ wqT, unsigned short* __restrict__ waT,
    const int* __restrict__ deg, int* __restrict__ tmp, int* __restrict__ bsum,
    int n, int effB, int wtB) {
  __shared__ int sh[256];
  const int bx = blockIdx.x;
  if (bx < effB) {
    int i = bx * 256 + threadIdx.x;
    const int total = LL * 2 * (CD + 1) * HH * DH;
    if (i >= total) return;
    int e = i & 31;
    int h = (i >> 5) & 3;
    int c = (i >> 7) % (CD + 1);
    int z = (i >> 7) / (CD + 1);
    int l = z >> 1, which = z & 1;
    const float* W = (which ? pWv : pWk) + (size_t)l * CD * CD;
    const float* B = (which ? pbv : pbk) + (size_t)l * CD;
    const float* R = (which ? pmr : par) + (size_t)l * HH * DH * DH + h * DH * DH;
    unsigned short* WoT = (which ? wveT : wkeT) + (size_t)l * CD * CD;
    float* Bo = (which ? bve : bke) + (size_t)l * CD;
    float acc = 0.f;
    if (c < CD) {
#pragma unroll
      for (int d = 0; d < DH; d++) acc += W[c * CD + h * DH + d] * R[d * DH + e];
      WoT[(size_t)(h * DH + e) * CD + c] = f2bfbits(acc);
    } else {
#pragma unroll
      for (int d = 0; d < DH; d++) acc += B[h * DH + d] * R[d * DH + e];
      Bo[h * DH + e] = acc;
    }
  } else if (bx < effB + wtB) {
    int i = (bx - effB) * 256 + threadIdx.x;  // < LL*2*CD*CD exactly
    int cin = i & 127;
    int cout = (i >> 7) & 127;
    int z = i >> 14;
    int l = z >> 1, which = z & 1;
    const float* W = (which ? pWa : pWq) + (size_t)l * CD * CD;
    unsigned short* WT = (which ? waT : wqT) + (size_t)l * CD * CD;
    WT[(size_t)cout * CD + cin] = f2bfbits(W[(size_t)cin * CD + cout]);
  } else {
    const int b = bx - effB - wtB;
    int i = b * 256 + threadIdx.x;
    int v = (i < n) ? deg[i] : 0;
    sh[threadIdx.x] = v;
    __syncthreads();
    for (int off = 1; off < 256; off <<= 1) {
      int t = (threadIdx.x >= off) ? sh[threadIdx.x - off] : 0;
      __syncthreads();
      sh[threadIdx.x] += t;
      __syncthreads();
    }
    if (i < n) tmp[i] = sh[threadIdx.x];
    if (threadIdx.x == 255) bsum[b] = sh[255];
  }
}

// ==== FUSED stage 3: {scan2, bscan} (r4, unchanged) ====
__global__ __launch_bounds__(256) void k_s2(
    int* __restrict__ bsum, int nb, const int* __restrict__ bcnt,
    int* __restrict__ bbase, int* __restrict__ bfill) {
  __shared__ int sh[256];
  __shared__ int carry;
  if (blockIdx.x == 0) {
    if (threadIdx.x == 0) carry = 0;
    __syncthreads();
    for (int base = 0; base < nb; base += 256) {
      int i = base + threadIdx.x;
      int v = (i < nb) ? bsum[i] : 0;
      sh[threadIdx.x] = v;
      __syncthreads();
      for (int off = 1; off < 256; off <<= 1) {
        int t = (threadIdx.x >= off) ? sh[threadIdx.x - off] : 0;
        __syncthreads();
        sh[threadIdx.x] += t;
        __syncthreads();
      }
      if (i < nb) bsum[i] = sh[threadIdx.x] + carry;
      __syncthreads();
      if (threadIdx.x == 0) carry += sh[255];
      __syncthreads();
    }
  } else {
    int t = threadIdx.x;
    int v = bcnt[t];
    sh[t] = v;
    __syncthreads();
    for (int off = 1; off < 256; off <<= 1) {
      int u = (t >= off) ? sh[t - off] : 0;
      __syncthreads();
      sh[t] += u;
      __syncthreads();
    }
    int excl = sh[t] - v;
    bbase[t] = excl;
    bfill[t] = excl;
  }
}

// ==== FUSED stage 4: {scan3, bin} (r4, unchanged) ====
__global__ __launch_bounds__(256) void k_s3bin(
    const int* __restrict__ tmp, const int* __restrict__ deg,
    const int* __restrict__ bsum, int* __restrict__ rowptr,
    int* __restrict__ fill, int n, int nB,
    const int* __restrict__ ei, int* __restrict__ bfill,
    int* __restrict__ ebs, int* __restrict__ ebd,
    const int* __restrict__ flags, int E, int Nn, int shift) {
  __shared__ int sS[BTILE];
  __shared__ int sD[BTILE];
  __shared__ int cnt[256], pref[256], base[256], lofs[256];
  const int bx = blockIdx.x;
  if (bx < nB) {
    int i = bx * 256 + threadIdx.x;
    if (i >= n) return;
    int off = (bx > 0) ? bsum[bx - 1] : 0;
    int excl = tmp[i] - deg[i] + off;
    rowptr[i] = excl;
    fill[i] = excl;
    return;
  }
  const int t = threadIdx.x;
  cnt[t] = 0;
  lofs[t] = 0;
  __syncthreads();
  const int t0 = (bx - nB) * BTILE;
  const int is64 = flags[1];
  for (int j = 0; j < 16; j++) {
    int i = t0 + t + j * 256;
    if (i < E) {
      int d = edge_idx(ei, (long)E + i, is64);
      if ((unsigned)d >= (unsigned)Nn) d = 0;
      atomicAdd(&cnt[d >> shift], 1);
    }
  }
  __syncthreads();
  {
    int v = cnt[t];
    pref[t] = v;
    __syncthreads();
    for (int off = 1; off < 256; off <<= 1) {
      int u = (t >= off) ? pref[t - off] : 0;
      __syncthreads();
      pref[t] += u;
      __syncthreads();
    }
    int incl = pref[t];
    __syncthreads();
    pref[t] = incl - v;
    base[t] = (v > 0) ? atomicAdd(&bfill[t], v) : 0;
  }
  __syncthreads();
  for (int j = 0; j < 16; j++) {
    int i = t0 + t + j * 256;
    if (i < E) {
      int s = edge_idx(ei, (long)i, is64);
      int d = edge_idx(ei, (long)E + i, is64);
      if ((unsigned)s >= (unsigned)Nn) s = 0;
      if ((unsigned)d >= (unsigned)Nn) d = 0;
      int b = d >> shift;
      int p = pref[b] + atomicAdd(&lofs[b], 1);
      sS[p] = s;
      sD[p] = d;
    }
  }
  __syncthreads();
  int tot = E - t0;
  if (tot > BTILE) tot = BTILE;
  for (int j = 0; j < 16; j++) {
    int i = t + j * 256;
    if (i < tot) {
      int d = sD[i];
      int b = d >> shift;
      int gp = base[b] + (i - pref[b]);
      ebs[gp] = sS[i];
      ebd[gp] = d;
    }
  }
}

// ==== FUSED {scatter2 || qkv-l0} (r12): the two are INDEPENDENT (scatter
// writes csr_src; qkv writes q/kv; edge0 — next dispatch — needs both).
// Role-split by blockIdx removes ~40us of serialization. ebs/ebd staging
// moved to the hbuf region (dead until gate_qkv) — the old kvbuf16 alias
// would race with the qkv role's kv writes. qkv body = r11 k_gemm_qkv
// (A loaded once, 3 sequential projections, XOR-swizzled LDS weights). ====
__global__ __launch_bounds__(256, 4) void k_sqkv(
    const int* __restrict__ bbase, const int* __restrict__ bcnt,
    const int* __restrict__ ebs, const int* __restrict__ ebd,
    int* __restrict__ fill, int* __restrict__ csr_src, int scatB,
    const void* __restrict__ Araw, const int* __restrict__ flags,
    const unsigned short* __restrict__ wq, const unsigned short* __restrict__ wk,
    const unsigned short* __restrict__ wv,
    const float* __restrict__ bq, const float* __restrict__ bk,
    const float* __restrict__ bv,
    float* __restrict__ qout, unsigned short* __restrict__ kvout, int nrows) {
  __shared__ unsigned short sW[128 * 128];
  const int bx = blockIdx.x;
  if (bx < scatB) {
    // ---- scatter role: per-bucket csr window fill (L2-local) ----
    int b = bx >> 1, half = bx & 1;
    int s0 = bbase[b], c = bcnt[b];
    int st = s0 + (half ? (c + 1) / 2 : 0);
    int en = s0 + (half ? c : (c + 1) / 2);
    for (int i = st + threadIdx.x; i < en; i += 256) {
      int s = ebs[i], d = ebd[i];
      int pos = atomicAdd(&fill[d], 1);
      csr_src[pos] = s;
    }
    return;
  }
  // ---- qkv role ----
  const int t = threadIdx.x;
  const int w = t >> 6;
  const int l = t & 63;
  const int r0 = (bx - scatB) * 64 + w * 16;
  const int lrow = l & 15;
  const int quad = l >> 4;
  const int k0 = quad * 8;
  const bool act = (r0 < nrows);
  const int srow = t >> 1;
  const int shf = t & 1;
  const int ax_f32 = flags[0];

  bf16x8 afr[4];
  if (act) {
    int ar = r0 + lrow;
    if (ar >= nrows) ar = nrows - 1;
#pragma unroll
    for (int kc = 0; kc < 4; kc++) {
      if (ax_f32) {
        const float* Af = (const float*)Araw + (size_t)ar * CD + kc * 32 + k0;
        float4 a = *(const float4*)Af;
        float4 b = *(const float4*)(Af + 4);
        afr[kc][0] = (short)f2bfbits(a.x); afr[kc][1] = (short)f2bfbits(a.y);
        afr[kc][2] = (short)f2bfbits(a.z); afr[kc][3] = (short)f2bfbits(a.w);
        afr[kc][4] = (short)f2bfbits(b.x); afr[kc][5] = (short)f2bfbits(b.y);
        afr[kc][6] = (short)f2bfbits(b.z); afr[kc][7] = (short)f2bfbits(b.w);
      } else {
        afr[kc] = *(const bf16x8*)((const unsigned short*)Araw +
                                   (size_t)ar * CD + kc * 32 + k0);
      }
    }
  }

#pragma unroll 1
  for (int which = 0; which < 3; which++) {
    const unsigned short* BT = (which == 0) ? wq : (which == 1) ? wk : wv;
    const float* bias = (which == 0) ? bq : (which == 1) ? bk : bv;
    {
      const unsigned short* src = BT + (size_t)srow * CD + shf * 64;
#pragma unroll
      for (int j = 0; j < 8; j++) {
        int c = shf * 8 + j;
        int cs = c ^ (srow & 15);
        *(uint4*)(&sW[srow * 128 + cs * 8]) = *(const uint4*)(src + j * 8);
      }
    }
    __syncthreads();
    if (act) {
      f32x4 acc[8];
#pragma unroll
      for (int ct = 0; ct < 8; ct++) {
        float b = bias[ct * 16 + lrow];
        acc[ct] = (f32x4){b, b, b, b};
      }
#pragma unroll
      for (int kc = 0; kc < 4; kc++) {
#pragma unroll
        for (int ct = 0; ct < 8; ct++) {
          int cs = (kc * 4 + quad) ^ lrow;
          bf16x8 bfr = *(const bf16x8*)(&sW[(ct * 16 + lrow) * 128 + cs * 8]);
          acc[ct] = __builtin_amdgcn_mfma_f32_16x16x32_bf16(afr[kc], bfr, acc[ct], 0, 0, 0);
        }
      }
#pragma unroll
      for (int ct = 0; ct < 8; ct++) {
#pragma unroll
        for (int i = 0; i < 4; i++) {
          int gr = r0 + quad * 4 + i;
          if (gr >= nrows) continue;
          int col = ct * 16 + lrow;
          float val = acc[ct][i];
          if (which == 0) {
            qout[(size_t)gr * CD + col] = val;
          } else {
            unsigned short* o = kvout + ((size_t)gr << 8) + ((which == 2) ? CD : 0);
            o[col] = f2bfbits(val);
          }
        }
      }
    }
    __syncthreads();
  }
}

// ==== FUSED gate-l0 + qkv-l1 (r12: K-SPLIT weight staging):
// sW halved to 128x64 (two-stage K halves, 8-chunk XOR swizzle: <=2-way
// conflicts = free tier). LDS 50.2 -> 33.8 KB => 4 blocks/CU (was 3);
// launch_bounds(256,4) (r9-verified reg regime). Math bit-identical. ====
__global__ __launch_bounds__(256, 4) void k_gate_qkv(
    const unsigned short* __restrict__ A, const unsigned short* __restrict__ BTa,
    const float* __restrict__ ba, const void* __restrict__ xres,
    float* __restrict__ h, const float* __restrict__ skip,
    const int* __restrict__ flags,
    const unsigned short* __restrict__ wq1, const unsigned short* __restrict__ wk1,
    const unsigned short* __restrict__ wv1,
    const float* __restrict__ bq1, const float* __restrict__ bk1,
    const float* __restrict__ bv1,
    float* __restrict__ qout, unsigned short* __restrict__ kvout, int nrows) {
  __shared__ unsigned short sA[64][136];
  __shared__ unsigned short sW[128 * 64];  // half-K, XOR-swizzled 16B chunks
  const int t = threadIdx.x;
  const int w = t >> 6;
  const int l = t & 63;
  const int blkbase = blockIdx.x * 64;
  const int r0 = blkbase + w * 16;
  const int lrow = l & 15;
  const int quad = l >> 4;
  const int k0 = quad * 8;
  const int xf32 = flags[0];
  const bool act = (r0 < nrows);
  const int srow = t >> 1;
  const int shf = t & 1;

  int ar = r0 + lrow;
  if (ar >= nrows) ar = nrows - 1;

  // ---- phase 1: gate, K-split halves ----
  f32x4 acc[8];
#pragma unroll
  for (int ct = 0; ct < 8; ct++) {
    float b = ba[ct * 16 + lrow];
    acc[ct] = (f32x4){b, b, b, b};
  }
  const unsigned short* Ap = A + (size_t)ar * CD;
#pragma unroll 1
  for (int hh = 0; hh < 2; hh++) {
    {
      const unsigned short* src = BTa + (size_t)srow * CD + hh * 64 + shf * 32;
#pragma unroll
      for (int j = 0; j < 4; j++) {
        int c = shf * 4 + j;
        int cs = c ^ (srow & 7);
        *(uint4*)(&sW[srow * 64 + cs * 8]) = *(const uint4*)(src + j * 8);
      }
    }
    __syncthreads();
    if (act) {
#pragma unroll
      for (int kcl = 0; kcl < 2; kcl++) {
        int kc = hh * 2 + kcl;
        bf16x8 af = *(const bf16x8*)(Ap + kc * 32 + k0);
#pragma unroll
        for (int ct = 0; ct < 8; ct++) {
          int cs = (kcl * 4 + quad) ^ (lrow & 7);
          bf16x8 bfr = *(const bf16x8*)(&sW[(ct * 16 + lrow) * 64 + cs * 8]);
          acc[ct] = __builtin_amdgcn_mfma_f32_16x16x32_bf16(af, bfr, acc[ct], 0, 0, 0);
        }
      }
    }
    __syncthreads();
  }
  if (act) {
    float gg = 1.f / (1.f + __expf(-skip[0]));
#pragma unroll
    for (int ct = 0; ct < 8; ct++) {
#pragma unroll
      for (int i = 0; i < 4; i++) {
        int gr = r0 + quad * 4 + i;
        if (gr >= nrows) continue;
        size_t ix = (size_t)gr * CD + ct * 16 + lrow;
        float hres = xf32 ? ((const float*)xres)[ix]
                          : bfbits2f((unsigned int)((const unsigned short*)xres)[ix]);
        float o = gg * acc[ct][i] + (1.f - gg) * hres;
        h[ix] = o;
        sA[gr - blkbase][ct * 16 + lrow] = f2bfbits(o);
      }
    }
  }
  __syncthreads();  // sA ready

  // ---- phase 2: qkv-l1; A from sA, weights K-split staged ----
  const unsigned short* Alds = &sA[ar - blkbase][0];
#pragma unroll 1
  for (int which = 0; which < 3; which++) {
    const unsigned short* BT = (which == 0) ? wq1 : (which == 1) ? wk1 : wv1;
    const float* bias = (which == 0) ? bq1 : (which == 1) ? bk1 : bv1;
    f32x4 acc2[8];
#pragma unroll
    for (int ct = 0; ct < 8; ct++) {
      float b = bias[ct * 16 + lrow];
      acc2[ct] = (f32x4){b, b, b, b};
    }
#pragma unroll 1
    for (int hh = 0; hh < 2; hh++) {
      {
        const unsigned short* src = BT + (size_t)srow * CD + hh * 64 + shf * 32;
#pragma unroll
        for (int j = 0; j < 4; j++) {
          int c = shf * 4 + j;
          int cs = c ^ (srow & 7);
          *(uint4*)(&sW[srow * 64 + cs * 8]) = *(const uint4*)(src + j * 8);
        }
      }
      __syncthreads();
      if (act) {
#pragma unroll
        for (int kcl = 0; kcl < 2; kcl++) {
          int kc = hh * 2 + kcl;
          bf16x8 af = *(const bf16x8*)(Alds + kc * 32 + k0);
#pragma unroll
          for (int ct = 0; ct < 8; ct++) {
            int cs = (kcl * 4 + quad) ^ (lrow & 7);
            bf16x8 bfr = *(const bf16x8*)(&sW[(ct * 16 + lrow) * 64 + cs * 8]);
            acc2[ct] = __builtin_amdgcn_mfma_f32_16x16x32_bf16(af, bfr, acc2[ct], 0, 0, 0);
          }
        }
      }
      __syncthreads();
    }
    if (act) {
#pragma unroll
      for (int ct = 0; ct < 8; ct++) {
#pragma unroll
        for (int i = 0; i < 4; i++) {
          int gr = r0 + quad * 4 + i;
          if (gr >= nrows) continue;
          int col = ct * 16 + lrow;
          float val = acc2[ct][i];
          if (which == 0) {
            qout[(size_t)gr * CD + col] = val;
          } else {
            unsigned short* o = kvout + ((size_t)gr << 8) + ((which == 2) ? CD : 0);
            o[col] = f2bfbits(val);
          }
        }
      }
    }
  }
}

// ==== gate MFMA GEMM, FINAL layer only (r11, unchanged — LDS staging). ====
__global__ __launch_bounds__(256, 4) void k_gemm_gate(
    const unsigned short* __restrict__ A, const unsigned short* __restrict__ BT,
    const float* __restrict__ bias, const float* __restrict__ h,
    const float* __restrict__ skip,
    const float* __restrict__ Wfc, const float* __restrict__ bfc,
    void* __restrict__ out, const int* __restrict__ flags, int nrows) {
  __shared__ unsigned short sW[128 * 128];
  const int t = threadIdx.x;
  const int w = t >> 6;
  const int l = t & 63;
  const int r0 = blockIdx.x * 64 + w * 16;
  const int lrow = l & 15;
  const int quad = l >> 4;
  const int k0 = quad * 8;
  const int xf32 = flags[0];
  const bool act = (r0 < nrows);
  const int srow = t >> 1;
  const int shf = t & 1;

  {
    const unsigned short* src = BT + (size_t)srow * CD + shf * 64;
#pragma unroll
    for (int j = 0; j < 8; j++) {
      int c = shf * 8 + j;
      int cs = c ^ (srow & 15);
      *(uint4*)(&sW[srow * 128 + cs * 8]) = *(const uint4*)(src + j * 8);
    }
  }
  __syncthreads();
  if (!act) return;

  f32x4 acc[8];
#pragma unroll
  for (int ct = 0; ct < 8; ct++) {
    float b = bias[ct * 16 + lrow];
    acc[ct] = (f32x4){b, b, b, b};
  }
  int ar = r0 + lrow;
  if (ar >= nrows) ar = nrows - 1;
  const unsigned short* Ap = A + (size_t)ar * CD;
#pragma unroll
  for (int kc = 0; kc < 4; kc++) {
    bf16x8 af = *(const bf16x8*)(Ap + kc * 32 + k0);
#pragma unroll
    for (int ct = 0; ct < 8; ct++) {
      int cs = (kc * 4 + quad) ^ lrow;
      bf16x8 bfr = *(const bf16x8*)(&sW[(ct * 16 + lrow) * 128 + cs * 8]);
      acc[ct] = __builtin_amdgcn_mfma_f32_16x16x32_bf16(af, bfr, acc[ct], 0, 0, 0);
    }
  }
  float gg = 1.f / (1.f + __expf(-skip[0]));
  float p0[4] = {0.f, 0.f, 0.f, 0.f};
  float p1[4] = {0.f, 0.f, 0.f, 0.f};
#pragma unroll
  for (int ct = 0; ct < 8; ct++) {
    float w0 = Wfc[(ct * 16 + lrow) * 2];
    float w1 = Wfc[(ct * 16 + lrow) * 2 + 1];
#pragma unroll
    for (int i = 0; i < 4; i++) {
      int gr = r0 + quad * 4 + i;
      if (gr >= nrows) continue;
      size_t ix = (size_t)gr * CD + ct * 16 + lrow;
      float o = gg * acc[ct][i] + (1.f - gg) * h[ix];
      p0[i] += o * w0;
      p1[i] += o * w1;
    }
  }
#pragma unroll
  for (int off = 1; off <= 8; off <<= 1) {
#pragma unroll
    for (int i = 0; i < 4; i++) {
      p0[i] += __shfl_xor(p0[i], off);
      p1[i] += __shfl_xor(p1[i], off);
    }
  }
  if (lrow == 0) {
#pragma unroll
    for (int i = 0; i < 4; i++) {
      int gr = r0 + quad * 4 + i;
      if (gr >= nrows) continue;
      float o0 = p0[i] + bfc[0];
      float o1 = p1[i] + bfc[1];
      if (xf32) {
        ((float*)out)[(size_t)gr * 2] = o0;
        ((float*)out)[(size_t)gr * 2 + 1] = o1;
      } else {
        ((bf16*)out)[(size_t)gr * 2] = __float2bfloat16(o0);
        ((bf16*)out)[(size_t)gr * 2 + 1] = __float2bfloat16(o1);
      }
    }
  }
}

// ---- per-edge compute: unpack k/v, dot with q, exp, accumulate ----
__device__ __forceinline__ void edge_acc(uint4 ku, uint4 vu, float4 qa, float4 qb,
                                         float* __restrict__ acc, float& den) {
  float k0 = bfbits2f(ku.x & 0xffffu), k1 = bfbits2f(ku.x >> 16);
  float k2 = bfbits2f(ku.y & 0xffffu), k3 = bfbits2f(ku.y >> 16);
  float k4 = bfbits2f(ku.z & 0xffffu), k5 = bfbits2f(ku.z >> 16);
  float k6 = bfbits2f(ku.w & 0xffffu), k7 = bfbits2f(ku.w >> 16);
  float v0 = bfbits2f(vu.x & 0xffffu), v1 = bfbits2f(vu.x >> 16);
  float v2 = bfbits2f(vu.y & 0xffffu), v3 = bfbits2f(vu.y >> 16);
  float v4 = bfbits2f(vu.z & 0xffffu), v5 = bfbits2f(vu.z >> 16);
  float v6 = bfbits2f(vu.w & 0xffffu), v7 = bfbits2f(vu.w >> 16);
  float pd = qa.x * k0 + qa.y * k1 + qa.z * k2 + qa.w * k3 +
             qb.x * k4 + qb.y * k5 + qb.z * k6 + qb.w * k7;
  pd += __shfl_xor(pd, 1);
  pd += __shfl_xor(pd, 2);
  float ew = __expf(fminf(pd, 60.f));  // no max-sub: |logit| ~ O(1), safe
  acc[0] += ew * v0; acc[1] += ew * v1;
  acc[2] += ew * v2; acc[3] += ew * v3;
  acc[4] += ew * v4; acc[5] += ew * v5;
  acc[6] += ew * v6; acc[7] += ew * v7;
  den += ew;
}

// ==== fused attention (unchanged; pinned at the random-512B L3/fabric
// throughput ceiling ~3.7 TB/s across 6 rounds of schedule changes). ====
__global__ __launch_bounds__(256) void k_edge(
    const float* __restrict__ q, const unsigned short* __restrict__ kv,
    const int* __restrict__ rowptr, const int* __restrict__ deg,
    const int* __restrict__ csr_src, const float* __restrict__ p_rel,
    unsigned short* __restrict__ agg16, int N) {
  int n = (blockIdx.x * 256 + threadIdx.x) >> 6;
  if (n >= N) return;
  const int lane = threadIdx.x & 63;
  const int g = lane >> 4;
  const int j = lane & 15;
  const int start = rowptr[n];
  const int end = start + deg[n];
  const float prl = p_rel[j >> 2] * 0.17677669529663687f;  // 1/sqrt(32)
  float4 qa = *(const float4*)(q + (size_t)n * CD + 8 * j);
  float4 qb = *(const float4*)(q + (size_t)n * CD + 8 * j + 4);
  qa.x *= prl; qa.y *= prl; qa.z *= prl; qa.w *= prl;
  qb.x *= prl; qb.y *= prl; qb.z *= prl; qb.w *= prl;
  float den = 0.f;
  float acc[8] = {0.f, 0.f, 0.f, 0.f, 0.f, 0.f, 0.f, 0.f};
  int e = start + g;
  if (e < end) {
    const int last = end - 1;
    bool bok = (e + 4) < end;
    int sa = csr_src[e];
    int sb = csr_src[bok ? e + 4 : e];
    const unsigned short* pa = kv + ((size_t)sa << 8) + 8 * j;
    const unsigned short* pb = kv + ((size_t)sb << 8) + 8 * j;
    uint4 kua = *(const uint4*)pa;
    uint4 vua = *(const uint4*)(pa + CD);
    uint4 kub = *(const uint4*)pb;
    uint4 vub = *(const uint4*)(pb + CD);
    for (;;) {
      const int en = e + 8;
      int ea2 = (en < last) ? en : last;
      int eb2 = (en + 4 < last) ? en + 4 : last;
      int sa2 = csr_src[ea2];
      int sb2 = csr_src[eb2];
      const unsigned short* pa2 = kv + ((size_t)sa2 << 8) + 8 * j;
      const unsigned short* pb2 = kv + ((size_t)sb2 << 8) + 8 * j;
      uint4 kua2 = *(const uint4*)pa2;
      uint4 vua2 = *(const uint4*)(pa2 + CD);
      uint4 kub2 = *(const uint4*)pb2;
      uint4 vub2 = *(const uint4*)(pb2 + CD);
      __builtin_amdgcn_sched_barrier(0);
      edge_acc(kua, vua, qa, qb, acc, den);
      if (bok) edge_acc(kub, vub, qa, qb, acc, den);
      if (en >= end) break;
      e = en;
      bok = (en + 4) < end;
      kua = kua2; vua = vua2; kub = kub2; vub = vub2;
    }
  }
#pragma unroll
  for (int off = 16; off <= 32; off <<= 1) {
    den += __shfl_xor(den, off);
#pragma unroll
    for (int i = 0; i < 8; i++) acc[i] += __shfl_xor(acc[i], off);
  }
  if (g == 0) {
    float inv = (den > 0.f) ? 1.f / den : 0.f;
    ushort4 o0, o1;
    o0.x = f2bfbits(gelu_f(acc[0] * inv)); o0.y = f2bfbits(gelu_f(acc[1] * inv));
    o0.z = f2bfbits(gelu_f(acc[2] * inv)); o0.w = f2bfbits(gelu_f(acc[3] * inv));
    o1.x = f2bfbits(gelu_f(acc[4] * inv)); o1.y = f2bfbits(gelu_f(acc[5] * inv));
    o1.z = f2bfbits(gelu_f(acc[6] * inv)); o1.w = f2bfbits(gelu_f(acc[7] * inv));
    *(ushort4*)(agg16 + (size_t)n * CD + 8 * j) = o0;
    *(ushort4*)(agg16 + (size_t)n * CD + 8 * j + 4) = o1;
  }
}

extern "C" void kernel_launch(void* const* d_in, const int* in_sizes, int n_in,
                              void* d_out, int out_size, void* d_ws, size_t ws_size,
                              hipStream_t stream) {
  const int* ei = (const int*)d_in[1];
  const int N = in_sizes[0] / CD;
  const int E = in_sizes[1] / 2;
  const size_t NC = (size_t)N * CD;
  const int nB = (N + 255) / 256;
  int shift = 0;
  while (((N - 1) >> shift) >= 256) shift++;  // 256 coarse buckets

  float* p = (float*)d_ws;
  float* hbuf = p;                                    // NC f32 (h1 storage)
  float* qbuf = p + NC;                               // NC f32
  float* cur = p + 2 * NC;
  unsigned short* kvbuf16 = (unsigned short*)cur; cur += NC;  // N x 256 bf16 (k|v)
  unsigned short* agg16 = (unsigned short*)cur; cur += NC / 2;
  int* ip = (int*)cur;
  int* deg = ip;
  int* tmp = ip + N;
  int* rowptr = ip + 2 * N;
  int* fill = ip + 3 * N;
  int* bsum = ip + 4 * N;
  int* csr_src = ip + 4 * N + nB;
  int* bcnt = csr_src + E;     // 256
  int* bbase = bcnt + 256;     // 256
  int* bfill = bbase + 256;    // 256
  cur = (float*)(bfill + 256);
  unsigned short* wkeT = (unsigned short*)cur; cur += (size_t)LL * CD * CD / 2;
  unsigned short* wveT = (unsigned short*)cur; cur += (size_t)LL * CD * CD / 2;
  unsigned short* wqT = (unsigned short*)cur; cur += (size_t)LL * CD * CD / 2;
  unsigned short* waT = (unsigned short*)cur; cur += (size_t)LL * CD * CD / 2;
  float* bke = cur; cur += (size_t)LL * CD;
  float* bve = cur; cur += (size_t)LL * CD;
  float* pblock = cur;
  float* pWk = cur; cur += (size_t)LL * CD * CD;
  float* pbk = cur; cur += (size_t)LL * CD;
  float* pWq = cur; cur += (size_t)LL * CD * CD;
  float* pbq = cur; cur += (size_t)LL * CD;
  float* pWv = cur; cur += (size_t)LL * CD * CD;
  float* pbv = cur; cur += (size_t)LL * CD;
  float* par = cur; cur += (size_t)LL * HH * DH * DH;
  float* pmr = cur; cur += (size_t)LL * HH * DH * DH;
  float* ppr = cur; cur += (size_t)LL * HH;
  float* pWa = cur; cur += (size_t)LL * CD * CD;
  float* pba = cur; cur += (size_t)LL * CD;
  float* pskip = cur; cur += LL;
  float* pWfc = cur; cur += (size_t)CD * 2;
  float* pbfc = cur; cur += 2;
  int* flags = (int*)cur;

  // binned-edge staging aliases hbuf (dead until gate_qkv writes h; the old
  // kvbuf16 alias would race with the fused qkv role's kv writes)
  int* ebs = (int*)hbuf;         // E ints
  int* ebd = ebs + E;            // E ints

  SegTab tab;
  const int sizes[NSEG] = {LL * CD * CD, LL * CD, LL * CD * CD, LL * CD,
                           LL * CD * CD, LL * CD, LL * HH * DH * DH,
                           LL * HH * DH * DH, LL * HH, LL * CD * CD, LL * CD,
                           LL, CD * 2, 2};
  const int srcIdx[NSEG] = {2, 3, 4, 5, 6, 7, 8, 9, 10, 11, 12, 13, 14, 15};
  int off = 0;
  for (int k = 0; k < NSEG; k++) {
    tab.src[k] = d_in[srcIdx[k]];
    tab.off[k] = off;
    off += sizes[k];
  }
  tab.total = off;

  hipMemsetAsync(deg, 0, (size_t)N * sizeof(int), stream);
  hipMemsetAsync(bcnt, 0, 256 * sizeof(int), stream);
  k_detect<<<1, 128, 0, stream>>>(d_in[0], ei, flags);

  const int parB = (tab.total + 255) / 256;
  const int histB = (E + BTILE - 1) / BTILE;
  k_pre<<<parB + histB, 256, 0, stream>>>(tab, pblock, ei, deg, bcnt, E, N,
                                          shift, flags, parB);

  const int effB = (LL * 2 * (CD + 1) * HH * DH + 255) / 256;
  const int wtB = (LL * 2 * CD * CD) / 256;
  k_w1<<<effB + wtB + nB, 256, 0, stream>>>(
      pWk, pbk, pWv, pbv, par, pmr, wkeT, bke, wveT, bve,
      pWq, pWa, wqT, waT, deg, tmp, bsum, N, effB, wtB);

  k_s2<<<2, 256, 0, stream>>>(bsum, nB, bcnt, bbase, bfill);
  k_s3bin<<<nB + histB, 256, 0, stream>>>(tmp, deg, bsum, rowptr, fill, N, nB,
                                          ei, bfill, ebs, ebd, flags, E, N, shift);

  const int mfmaBlocks = (N + 63) / 64;

  // fused: scatter2 || qkv-l0 (independent; edge0 needs both next dispatch)
  k_sqkv<<<512 + mfmaBlocks, 256, 0, stream>>>(
      bbase, bcnt, ebs, ebd, fill, csr_src, 512,
      d_in[0], flags, wqT, wkeT, wveT, pbq, bke, bve, qbuf, kvbuf16, N);

  // layer 0 edge attention
  k_edge<<<(N + 3) / 4, 256, 0, stream>>>(qbuf, kvbuf16, rowptr, deg,
                                          csr_src, ppr, agg16, N);

  // fused: gate-l0 (residual from x) + qkv-l1 (A + K-split weights from LDS)
  k_gate_qkv<<<mfmaBlocks, 256, 0, stream>>>(
      agg16, waT, pba, d_in[0], hbuf, pskip, flags,
      wqT + (size_t)CD * CD, wkeT + (size_t)CD * CD, wveT + (size_t)CD * CD,
      pbq + CD, bke + CD, bve + CD, qbuf, kvbuf16, N);

  // layer 1 edge attention
  k_edge<<<(N + 3) / 4, 256, 0, stream>>>(qbuf, kvbuf16, rowptr, deg,
                                          csr_src, ppr + HH, agg16, N);

  // layer 1 gate + fused final projection (LDS-staged weights)
  k_gemm_gate<<<mfmaBlocks, 256, 0, stream>>>(
      agg16, waT + (size_t)CD * CD, pba + CD, hbuf, pskip + 1,
      pWfc, pbfc, d_out, flags, N);
}